// Round 17
// baseline (269.928 us; speedup 1.0000x reference)
//
#include <hip/hip_runtime.h>

typedef unsigned short u16;
typedef unsigned int u32;
typedef __bf16 bf16x8 __attribute__((ext_vector_type(8)));
typedef __bf16 b16x4 __attribute__((ext_vector_type(4)));
typedef short s16x4 __attribute__((ext_vector_type(4)));
typedef float f32x4 __attribute__((ext_vector_type(4)));

#define SCALE 0.07905694150420949f   // (128+32)^-0.5
#define LOG2E 1.4426950408889634f

__device__ __forceinline__ float bf2f(u16 h) { return __uint_as_float(((u32)h) << 16); }
__device__ __forceinline__ u16 f2bf(float f) {  // RNE-ish
  u32 u = __float_as_uint(f);
  u += 0x7fffu + ((u >> 16) & 1u);
  return (u16)(u >> 16);
}
__device__ __forceinline__ bf16x8 ldfrag(const u16* p) {
  int4 t = *reinterpret_cast<const int4*>(p);
  return __builtin_bit_cast(bf16x8, t);
}

// 16x16x16 bf16 MFMA (A,B = 4 bf16 per lane, k = 4*(lane>>4)+j)
__device__ __forceinline__ f32x4 mfma16x16(s16x4 a, s16x4 b, f32x4 c) {
#if __has_builtin(__builtin_amdgcn_mfma_f32_16x16x16bf16_1k)
  return __builtin_amdgcn_mfma_f32_16x16x16bf16_1k(a, b, c, 0, 0, 0);
#elif __has_builtin(__builtin_amdgcn_mfma_f32_16x16x16_bf16)
  return __builtin_amdgcn_mfma_f32_16x16x16_bf16(__builtin_bit_cast(b16x4, a),
                                                 __builtin_bit_cast(b16x4, b), c, 0, 0, 0);
#else
  asm volatile("s_nop 2\n\tv_mfma_f32_16x16x16_bf16 %0, %1, %2, %0"
               : "+v"(c) : "v"(a), "v"(b));
  return c;
#endif
}

// async global->LDS, 16B per lane (dest = wave-uniform base + lane*16)
__device__ __forceinline__ void gld16(const u16* g, u16* l) {
  __builtin_amdgcn_global_load_lds((const __attribute__((address_space(1))) u32*)(const void*)g,
                                   (__attribute__((address_space(3))) u32*)(void*)l, 16, 0, 0);
}

// ---------------- merged f32 -> bf16 converts (one launch) ----------------
__global__ void conv_all(const float* __restrict__ hs, const float* __restrict__ qw,
                         const float* __restrict__ kw, const float* __restrict__ vw,
                         const float* __restrict__ ow, u16* __restrict__ hs_bf,
                         u16* __restrict__ wqkv, u16* __restrict__ ow_bf) {
  const int total = 4718592;
  for (int i = blockIdx.x * blockDim.x + threadIdx.x; i < total; i += gridDim.x * blockDim.x) {
    const float* src;
    u16* dst;
    int j = i;
    if (j < 2097152) {
      src = hs; dst = hs_bf;
    } else if (j < 3145728) {
      j -= 2097152; src = qw; dst = wqkv;
    } else if (j < 3407872) {
      j -= 3145728; src = kw; dst = wqkv + 4194304;
    } else if (j < 3670016) {
      j -= 3407872; src = vw; dst = wqkv + 5242880;
    } else {
      j -= 3670016; src = ow; dst = ow_bf;
    }
    float4 v = reinterpret_cast<const float4*>(src)[j];
    ushort4 o = {f2bf(v.x), f2bf(v.y), f2bf(v.z), f2bf(v.w)};
    reinterpret_cast<ushort4*>(dst)[j] = o;
  }
}

// ---------------- GEMM v3 (round-10 proven): 128x128, counted vmcnt(8), 2-deep ----------------
template <int OUT_BF16>
__global__ __launch_bounds__(256, 2) void gemm_bt(const u16* __restrict__ A,
                                                  const u16* __restrict__ Bw,
                                                  void* __restrict__ Cv,
                                                  int M, int N, int K) {
  __shared__ __align__(16) u16 As[2][8192];
  __shared__ __align__(16) u16 Bs[2][8192];
  const int tid = threadIdx.x;
  const int nbn = N >> 7;
  const int cpx = gridDim.x >> 3;
  const int swz = (blockIdx.x & 7) * cpx + (blockIdx.x >> 3);
  const int bm = swz / nbn, bn = swz % nbn;
  const int row0 = bm << 7, col0 = bn << 7;
  const int lane = tid & 63, w = tid >> 6;
  const int lg = lane >> 4, lr = lane & 15;
  const int wr = w >> 1, wc = w & 1;
  const int nt = K >> 6;

  auto stage = [&](int slot, int t) {
    const size_t k0 = (size_t)t << 6;
#pragma unroll
    for (int it = 0; it < 4; ++it) {
      int G = it * 256 + tid;
      int r = G >> 3, p = G & 7;
      int gs = p ^ (r & 7);
      gld16(&A[(size_t)(row0 + r) * K + k0 + gs * 8], &As[slot][(size_t)G * 8]);
      gld16(&Bw[(size_t)(col0 + r) * K + k0 + gs * 8], &Bs[slot][(size_t)G * 8]);
    }
  };

  f32x4 acc[4][4] = {};
  stage(0, 0);
  if (nt > 1) stage(1, 1);

  for (int t = 0; t < nt; ++t) {
    const int slot = t & 1;
    if (t + 1 < nt) {
      asm volatile("s_waitcnt vmcnt(8)" ::: "memory");
    } else {
      asm volatile("s_waitcnt vmcnt(0)" ::: "memory");
    }
    __builtin_amdgcn_s_barrier();
    __builtin_amdgcn_sched_barrier(0);
#pragma unroll
    for (int kk = 0; kk < 2; ++kk) {
      bf16x8 af[4], bv[4];
#pragma unroll
      for (int m = 0; m < 4; ++m) {
        int r = wr * 64 + m * 16 + lr;
        int g = (kk * 4 + lg) ^ (lr & 7);
        af[m] = ldfrag(&As[slot][r * 64 + g * 8]);
      }
#pragma unroll
      for (int n = 0; n < 4; ++n) {
        int r = wc * 64 + n * 16 + lr;
        int g = (kk * 4 + lg) ^ (lr & 7);
        bv[n] = ldfrag(&Bs[slot][r * 64 + g * 8]);
      }
#pragma unroll
      for (int m = 0; m < 4; ++m)
#pragma unroll
        for (int n = 0; n < 4; ++n)
          acc[m][n] = __builtin_amdgcn_mfma_f32_16x16x32_bf16(af[m], bv[n], acc[m][n], 0, 0, 0);
    }
    __builtin_amdgcn_sched_barrier(0);
    __builtin_amdgcn_s_barrier();
    if (t + 2 < nt) stage(slot, t + 2);
  }

#pragma unroll
  for (int m = 0; m < 4; ++m)
#pragma unroll
    for (int n = 0; n < 4; ++n)
#pragma unroll
      for (int r = 0; r < 4; ++r) {
        int row = row0 + wr * 64 + m * 16 + lg * 4 + r;
        int col = col0 + wc * 64 + n * 16 + lr;
        float v = acc[m][n][r];
        if (OUT_BF16)
          ((u16*)Cv)[(size_t)row * N + col] = f2bf(v);
        else
          ((float*)Cv)[(size_t)row * N + col] = v;
      }
}

// ---------------- postprocess: RMSNorm heads + behavior embed concat + V transpose ----------------
// q is pre-scaled by SCALE*log2e (attention computes softmax in exp2 domain).
__global__ __launch_bounds__(256) void postproc(
    const u16* __restrict__ qkv, const int* __restrict__ bidx,
    const float* __restrict__ qnw, const float* __restrict__ knw,
    const float* __restrict__ qbe_t, const float* __restrict__ kbe_t,
    const float* __restrict__ qbn, const float* __restrict__ kbn,
    u16* __restrict__ qcat, u16* __restrict__ kcat, u16* __restrict__ vt) {
  const int tok = blockIdx.x;
  const int b = tok >> 11, s = tok & 2047;
  const int w = threadIdx.x >> 6, lane = threadIdx.x & 63;
  const int idx = bidx[tok];
  const u16* base = qkv + (size_t)tok * 3072;
  const float QS = SCALE * LOG2E;

  for (int h = w; h < 16; h += 4) {
    float x0 = bf2f(base[h * 128 + 2 * lane]);
    float x1 = bf2f(base[h * 128 + 2 * lane + 1]);
    float ss = x0 * x0 + x1 * x1;
#pragma unroll
    for (int o = 32; o; o >>= 1) ss += __shfl_xor(ss, o);
    float rn = rsqrtf(ss * (1.f / 128.f) + 1e-6f) * QS;
    size_t ob = ((size_t)(b * 16 + h) * 2048 + s) * 160;
    u32 pk = (u32)f2bf(x0 * rn * qnw[2 * lane]) |
             ((u32)f2bf(x1 * rn * qnw[2 * lane + 1]) << 16);
    *reinterpret_cast<u32*>(&qcat[ob + 2 * lane]) = pk;
    if (lane < 32) {
      float e = qbe_t[idx * 512 + h * 32 + lane];
      float s2 = e * e;
#pragma unroll
      for (int o = 16; o; o >>= 1) s2 += __shfl_xor(s2, o);
      qcat[ob + 128 + lane] = f2bf(e * rsqrtf(s2 * (1.f / 32.f) + 1e-6f) * qbn[lane] * QS);
    }
  }
  {
    const int kv = w;
    float x0 = bf2f(base[2048 + kv * 128 + 2 * lane]);
    float x1 = bf2f(base[2048 + kv * 128 + 2 * lane + 1]);
    float ss = x0 * x0 + x1 * x1;
#pragma unroll
    for (int o = 32; o; o >>= 1) ss += __shfl_xor(ss, o);
    float rn = rsqrtf(ss * (1.f / 128.f) + 1e-6f);
    size_t ob = ((size_t)(b * 4 + kv) * 2048 + s) * 160;
    u32 pk = (u32)f2bf(x0 * rn * knw[2 * lane]) |
             ((u32)f2bf(x1 * rn * knw[2 * lane + 1]) << 16);
    *reinterpret_cast<u32*>(&kcat[ob + 2 * lane]) = pk;
    if (lane < 32) {
      float e = kbe_t[idx * 128 + kv * 32 + lane];
      float s2 = e * e;
#pragma unroll
      for (int o = 16; o; o >>= 1) s2 += __shfl_xor(s2, o);
      kcat[ob + 128 + lane] = f2bf(e * rsqrtf(s2 * (1.f / 32.f) + 1e-6f) * kbn[lane]);
    }
    size_t vb = (size_t)(b * 4 + kv) * 128 * 2048;
    vt[vb + (size_t)lane * 2048 + s] = base[2560 + kv * 128 + lane];
    vt[vb + (size_t)(lane + 64) * 2048 + s] = base[2560 + kv * 128 + 64 + lane];
  }
}

// ---------------- flash attention v8 + balanced g + native-cast P-pack ----------------
__global__ __launch_bounds__(256, 2) void attn(const u16* __restrict__ qcat,
                                               const u16* __restrict__ kcat,
                                               const u16* __restrict__ vt,
                                               u16* __restrict__ aout) {
  __shared__ __align__(16) u16 Kls[2][10240];  // [64 rows][20 granules of 8] swizzled
  __shared__ __align__(16) u16 Vls[8192];      // V^T [128 d][8 granules of 8 keys] swizzled
  const int tid = threadIdx.x;
  const int blk = blockIdx.x;
  const int kvh = blk & 3;
  const int b = (blk >> 2) & 1;
  const int hq = (blk >> 3) & 3;
  const int gsel = blk >> 5;  // 0..15
  const int g = (gsel < 8) ? gsel : 23 - gsel;  // 0..7 then 15..8 (pairs sum to 15)
  const int h = kvh * 4 + hq;
  const int w = tid >> 6;
  const int lane = tid & 63;
  const int lg = lane >> 4, lr = lane & 15;
  const int qb_a = g * 4 + w;        // 0..63
  const int qb_b = 127 - qb_a;       // 64..127
  const int qpa = qb_a * 16 + lr;
  const int qpb = qb_b * 16 + lr;
  const int nt = 32 - g;             // tiles: uniform across the block's waves

  const u16* qpA = qcat + ((size_t)(b * 16 + h) * 2048 + qb_a * 16) * 160;
  const u16* qpB = qcat + ((size_t)(b * 16 + h) * 2048 + qb_b * 16) * 160;
  bf16x8 qfa[5], qfb[5];
#pragma unroll
  for (int c = 0; c < 5; ++c) {
    qfa[c] = ldfrag(qpA + lr * 160 + c * 32 + lg * 8);
    qfb[c] = ldfrag(qpB + lr * 160 + c * 32 + lg * 8);
  }

  const u16* kbp = kcat + (size_t)(b * 4 + kvh) * 2048 * 160;
  const u16* vbp = vt + (size_t)(b * 4 + kvh) * 128 * 2048;

  auto stageK = [&](int buf, int kt) {
    const u16* ksrc = kbp + (size_t)kt * (64 * 160);
#pragma unroll
    for (int it = 0; it < 5; ++it) {
      int G = it * 256 + tid;
      int r = G / 20, p = G - r * 20;
      int gs = p ^ ((r >> 1) & 3);
      gld16(ksrc + r * 160 + gs * 8, &Kls[buf][G * 8]);
    }
  };
  auto stageV = [&](int kt) {
    const u16* vsrc = vbp + kt * 64;
#pragma unroll
    for (int it = 0; it < 4; ++it) {
      int G = it * 256 + tid;
      int r = G >> 3, p = G & 7;
      int gs = p ^ (r & 7);
      gld16(vsrc + (size_t)r * 2048 + gs * 8, &Vls[G * 8]);
    }
  };

  float ma = -INFINITY, la = 0.f, mb = -INFINITY, lb = 0.f;
  f32x4 acc_a[8] = {}, acc_b[8] = {};

  stageK(0, 0);
  stageV(0);
  __syncthreads();

  for (int kt = 0; kt < nt; ++kt) {
    const int buf = kt & 1;
    const bool aact = (kt <= g);
    if (kt + 1 < nt) stageK(buf ^ 1, kt + 1);

    f32x4 sa[4] = {}, sb[4] = {};
#pragma unroll
    for (int c = 0; c < 5; ++c) {
      bf16x8 kf[4];
#pragma unroll
      for (int i = 0; i < 4; ++i) {
        int r = i * 16 + lr;
        int p = (c * 4 + lg) ^ ((r >> 1) & 3);
        kf[i] = ldfrag(&Kls[buf][(r * 20 + p) * 8]);
      }
#pragma unroll
      for (int i = 0; i < 4; ++i)
        sb[i] = __builtin_amdgcn_mfma_f32_16x16x32_bf16(kf[i], qfb[c], sb[i], 0, 0, 0);
      if (aact)
#pragma unroll
        for (int i = 0; i < 4; ++i)
          sa[i] = __builtin_amdgcn_mfma_f32_16x16x32_bf16(kf[i], qfa[c], sa[i], 0, 0, 0);
    }

    // --- softmax in exp2 domain (q pre-scaled by SCALE*log2e), defer-max THR=8 ---
    s16x4 pka[4], pkb[4];
    auto soft = [&](f32x4 (&st)[4], float& mm, float& ls, f32x4 (&ac)[8], s16x4 (&pk)[4],
                    bool masked, int qpos) {
      float vmax = -INFINITY;
#pragma unroll
      for (int i = 0; i < 4; ++i)
#pragma unroll
        for (int r = 0; r < 4; ++r) {
          float v = st[i][r];
          if (masked && (kt * 64 + i * 16 + 4 * lg + r > qpos)) v = -INFINITY;
          st[i][r] = v;
          vmax = fmaxf(vmax, v);
        }
      vmax = fmaxf(vmax, __shfl_xor(vmax, 16));
      vmax = fmaxf(vmax, __shfl_xor(vmax, 32));
      bool skip = __all(vmax <= mm + 8.f);  // defer-max: P bounded by 2^8
      float mn = skip ? mm : fmaxf(mm, vmax);
      float rs = 0.f;
#pragma unroll
      for (int i = 0; i < 4; ++i)
#pragma unroll
        for (int r = 0; r < 4; ++r) {
          float p = exp2f(st[i][r] - mn);
          st[i][r] = p;
          rs += p;
        }
      rs += __shfl_xor(rs, 16);
      rs += __shfl_xor(rs, 32);
      if (skip) {
        ls += rs;
      } else {
        float corr = exp2f(mm - mn);
        ls = ls * corr + rs;
        mm = mn;
        float c4[4];
#pragma unroll
        for (int r = 0; r < 4; ++r) c4[r] = __shfl(corr, 4 * lg + r);
#pragma unroll
        for (int dt = 0; dt < 8; ++dt)
#pragma unroll
          for (int r = 0; r < 4; ++r) ac[dt][r] *= c4[r];
      }
      // native-cast P-pack: compiler pairs these into v_cvt_pk_bf16_f32 (T12 note: never
      // hand-write the asm; the NATIVE cast is the fast path)
#pragma unroll
      for (int i = 0; i < 4; ++i) {
        b16x4 t;
        t[0] = (__bf16)st[i][0];
        t[1] = (__bf16)st[i][1];
        t[2] = (__bf16)st[i][2];
        t[3] = (__bf16)st[i][3];
        pk[i] = __builtin_bit_cast(s16x4, t);
      }
    };
    soft(sb, mb, lb, acc_b, pkb, kt == nt - 1, qpb);
    if (aact) soft(sa, ma, la, acc_a, pka, kt == g, qpa);

    __syncthreads();  // #1: V(kt) staged by all waves is complete

#pragma unroll
    for (int ks = 0; ks < 4; ++ks) {
      s16x4 vf[8];
#pragma unroll
      for (int dt = 0; dt < 8; ++dt) {
        int r = dt * 16 + lr;
        int p = (ks * 2 + (lg >> 1)) ^ (r & 7);
        vf[dt] = *reinterpret_cast<const s16x4*>(&Vls[(r * 8 + p) * 8 + (lg & 1) * 4]);
      }
#pragma unroll
      for (int dt = 0; dt < 8; ++dt) acc_b[dt] = mfma16x16(pkb[ks], vf[dt], acc_b[dt]);
      if (aact)
#pragma unroll
        for (int dt = 0; dt < 8; ++dt) acc_a[dt] = mfma16x16(pka[ks], vf[dt], acc_a[dt]);
    }

    __syncthreads();  // #2: all waves done reading Vls
    if (kt + 1 < nt) stageV(kt + 1);
  }

  float inva[4], invb[4];
#pragma unroll
  for (int r = 0; r < 4; ++r) {
    inva[r] = 1.f / __shfl(la, 4 * lg + r);
    invb[r] = 1.f / __shfl(lb, 4 * lg + r);
  }
#pragma unroll
  for (int dt = 0; dt < 8; ++dt)
#pragma unroll
    for (int r = 0; r < 4; ++r) {
      int rowa = qb_a * 16 + 4 * lg + r;
      int rowb = qb_b * 16 + 4 * lg + r;
      aout[((size_t)(b * 2048 + rowa) * 16 + h) * 128 + dt * 16 + lr] =
          f2bf(acc_a[dt][r] * inva[r]);
      aout[((size_t)(b * 2048 + rowb) * 16 + h) * 128 + dt * 16 + lr] =
          f2bf(acc_b[dt][r] * invb[r]);
    }
}

extern "C" void kernel_launch(void* const* d_in, const int* in_sizes, int n_in,
                              void* d_out, int out_size, void* d_ws, size_t ws_size,
                              hipStream_t stream) {
  const float* hs = (const float*)d_in[0];
  const int* bidx = (const int*)d_in[1];
  const float* qw = (const float*)d_in[2];
  const float* kw = (const float*)d_in[3];
  const float* vw = (const float*)d_in[4];
  const float* ow = (const float*)d_in[5];
  const float* qnw = (const float*)d_in[6];
  const float* knw = (const float*)d_in[7];
  const float* qbe_t = (const float*)d_in[8];
  const float* kbe_t = (const float*)d_in[9];
  const float* qbn = (const float*)d_in[10];
  const float* kbn = (const float*)d_in[11];

  u16* ws = (u16*)d_ws;
  u16* hs_bf = ws;                       // 4096*2048
  u16* wqkv = hs_bf + 8388608;           // 3072*2048
  u16* ow_bf = wqkv + 6291456;           // 2048*2048
  u16* qkv = ow_bf + 4194304;            // 4096*3072
  u16* qcat = qkv + 12582912;            // 2*16*2048*160
  u16* kcat = qcat + 10485760;           // 2*4*2048*160
  u16* vt = kcat + 2621440;              // 2*4*128*2048
  u16* attn_o = vt + 2097152;            // 4096*2048

  conv_all<<<4608, 256, 0, stream>>>(hs, qw, kw, vw, ow, hs_bf, wqkv, ow_bf);

  gemm_bt<1><<<dim3((4096 / 128) * (3072 / 128)), 256, 0, stream>>>(
      hs_bf, wqkv, (void*)qkv, 4096, 3072, 2048);

  postproc<<<4096, 256, 0, stream>>>(qkv, bidx, qnw, knw, qbe_t, kbe_t, qbn, kbn,
                                     qcat, kcat, vt);

  attn<<<512, 256, 0, stream>>>(qcat, kcat, vt, attn_o);

  gemm_bt<0><<<dim3((4096 / 128) * (2048 / 128)), 256, 0, stream>>>(
      attn_o, ow_bf, (void*)d_out, 4096, 2048, 2048);
}

// Round 18
// 223.103 us; speedup vs baseline: 1.2099x; 1.2099x over previous
//
#include <hip/hip_runtime.h>

typedef unsigned short u16;
typedef unsigned int u32;
typedef __bf16 bf16x8 __attribute__((ext_vector_type(8)));
typedef __bf16 b16x4 __attribute__((ext_vector_type(4)));
typedef short s16x4 __attribute__((ext_vector_type(4)));
typedef float f32x4 __attribute__((ext_vector_type(4)));

#define SCALE 0.07905694150420949f   // (128+32)^-0.5
#define LOG2E 1.4426950408889634f

__device__ __forceinline__ float bf2f(u16 h) { return __uint_as_float(((u32)h) << 16); }
__device__ __forceinline__ u16 f2bf(float f) {  // RNE-ish
  u32 u = __float_as_uint(f);
  u += 0x7fffu + ((u >> 16) & 1u);
  return (u16)(u >> 16);
}
__device__ __forceinline__ u16 f2bf_fast(float f) {  // round-half-up, for attention P
  return (u16)((__float_as_uint(f) + 0x8000u) >> 16);
}
__device__ __forceinline__ bf16x8 ldfrag(const u16* p) {
  int4 t = *reinterpret_cast<const int4*>(p);
  return __builtin_bit_cast(bf16x8, t);
}

// 16x16x16 bf16 MFMA (A,B = 4 bf16 per lane, k = 4*(lane>>4)+j)
__device__ __forceinline__ f32x4 mfma16x16(s16x4 a, s16x4 b, f32x4 c) {
#if __has_builtin(__builtin_amdgcn_mfma_f32_16x16x16bf16_1k)
  return __builtin_amdgcn_mfma_f32_16x16x16bf16_1k(a, b, c, 0, 0, 0);
#elif __has_builtin(__builtin_amdgcn_mfma_f32_16x16x16_bf16)
  return __builtin_amdgcn_mfma_f32_16x16x16_bf16(__builtin_bit_cast(b16x4, a),
                                                 __builtin_bit_cast(b16x4, b), c, 0, 0, 0);
#else
  asm volatile("s_nop 2\n\tv_mfma_f32_16x16x16_bf16 %0, %1, %2, %0"
               : "+v"(c) : "v"(a), "v"(b));
  return c;
#endif
}

// async global->LDS, 16B per lane (dest = wave-uniform base + lane*16)
__device__ __forceinline__ void gld16(const u16* g, u16* l) {
  __builtin_amdgcn_global_load_lds((const __attribute__((address_space(1))) u32*)(const void*)g,
                                   (__attribute__((address_space(3))) u32*)(void*)l, 16, 0, 0);
}

// ---------------- merged f32 -> bf16 converts (one launch) ----------------
__global__ void conv_all(const float* __restrict__ hs, const float* __restrict__ qw,
                         const float* __restrict__ kw, const float* __restrict__ vw,
                         const float* __restrict__ ow, u16* __restrict__ hs_bf,
                         u16* __restrict__ wqkv, u16* __restrict__ ow_bf) {
  const int total = 4718592;
  for (int i = blockIdx.x * blockDim.x + threadIdx.x; i < total; i += gridDim.x * blockDim.x) {
    const float* src;
    u16* dst;
    int j = i;
    if (j < 2097152) {
      src = hs; dst = hs_bf;
    } else if (j < 3145728) {
      j -= 2097152; src = qw; dst = wqkv;
    } else if (j < 3407872) {
      j -= 3145728; src = kw; dst = wqkv + 4194304;
    } else if (j < 3670016) {
      j -= 3407872; src = vw; dst = wqkv + 5242880;
    } else {
      j -= 3670016; src = ow; dst = ow_bf;
    }
    float4 v = reinterpret_cast<const float4*>(src)[j];
    ushort4 o = {f2bf(v.x), f2bf(v.y), f2bf(v.z), f2bf(v.w)};
    reinterpret_cast<ushort4*>(dst)[j] = o;
  }
}

// ---------------- GEMM v3 (round-10 proven): 128x128, counted vmcnt(8), 2-deep ----------------
template <int OUT_BF16>
__global__ __launch_bounds__(256, 2) void gemm_bt(const u16* __restrict__ A,
                                                  const u16* __restrict__ Bw,
                                                  void* __restrict__ Cv,
                                                  int M, int N, int K) {
  __shared__ __align__(16) u16 As[2][8192];
  __shared__ __align__(16) u16 Bs[2][8192];
  const int tid = threadIdx.x;
  const int nbn = N >> 7;
  const int cpx = gridDim.x >> 3;
  const int swz = (blockIdx.x & 7) * cpx + (blockIdx.x >> 3);
  const int bm = swz / nbn, bn = swz % nbn;
  const int row0 = bm << 7, col0 = bn << 7;
  const int lane = tid & 63, w = tid >> 6;
  const int lg = lane >> 4, lr = lane & 15;
  const int wr = w >> 1, wc = w & 1;
  const int nt = K >> 6;

  auto stage = [&](int slot, int t) {
    const size_t k0 = (size_t)t << 6;
#pragma unroll
    for (int it = 0; it < 4; ++it) {
      int G = it * 256 + tid;
      int r = G >> 3, p = G & 7;
      int gs = p ^ (r & 7);
      gld16(&A[(size_t)(row0 + r) * K + k0 + gs * 8], &As[slot][(size_t)G * 8]);
      gld16(&Bw[(size_t)(col0 + r) * K + k0 + gs * 8], &Bs[slot][(size_t)G * 8]);
    }
  };

  f32x4 acc[4][4] = {};
  stage(0, 0);
  if (nt > 1) stage(1, 1);

  for (int t = 0; t < nt; ++t) {
    const int slot = t & 1;
    if (t + 1 < nt) {
      asm volatile("s_waitcnt vmcnt(8)" ::: "memory");
    } else {
      asm volatile("s_waitcnt vmcnt(0)" ::: "memory");
    }
    __builtin_amdgcn_s_barrier();
    __builtin_amdgcn_sched_barrier(0);
#pragma unroll
    for (int kk = 0; kk < 2; ++kk) {
      bf16x8 af[4], bv[4];
#pragma unroll
      for (int m = 0; m < 4; ++m) {
        int r = wr * 64 + m * 16 + lr;
        int g = (kk * 4 + lg) ^ (lr & 7);
        af[m] = ldfrag(&As[slot][r * 64 + g * 8]);
      }
#pragma unroll
      for (int n = 0; n < 4; ++n) {
        int r = wc * 64 + n * 16 + lr;
        int g = (kk * 4 + lg) ^ (lr & 7);
        bv[n] = ldfrag(&Bs[slot][r * 64 + g * 8]);
      }
#pragma unroll
      for (int m = 0; m < 4; ++m)
#pragma unroll
        for (int n = 0; n < 4; ++n)
          acc[m][n] = __builtin_amdgcn_mfma_f32_16x16x32_bf16(af[m], bv[n], acc[m][n], 0, 0, 0);
    }
    __builtin_amdgcn_sched_barrier(0);
    __builtin_amdgcn_s_barrier();
    if (t + 2 < nt) stage(slot, t + 2);
  }

#pragma unroll
  for (int m = 0; m < 4; ++m)
#pragma unroll
    for (int n = 0; n < 4; ++n)
#pragma unroll
      for (int r = 0; r < 4; ++r) {
        int row = row0 + wr * 64 + m * 16 + lg * 4 + r;
        int col = col0 + wc * 64 + n * 16 + lr;
        float v = acc[m][n][r];
        if (OUT_BF16)
          ((u16*)Cv)[(size_t)row * N + col] = f2bf(v);
        else
          ((float*)Cv)[(size_t)row * N + col] = v;
      }
}

// ---------------- postprocess: RMSNorm heads + behavior embed concat + V transpose ----------------
// q is pre-scaled by SCALE*log2e (attention computes softmax in exp2 domain).
__global__ __launch_bounds__(256) void postproc(
    const u16* __restrict__ qkv, const int* __restrict__ bidx,
    const float* __restrict__ qnw, const float* __restrict__ knw,
    const float* __restrict__ qbe_t, const float* __restrict__ kbe_t,
    const float* __restrict__ qbn, const float* __restrict__ kbn,
    u16* __restrict__ qcat, u16* __restrict__ kcat, u16* __restrict__ vt) {
  const int tok = blockIdx.x;
  const int b = tok >> 11, s = tok & 2047;
  const int w = threadIdx.x >> 6, lane = threadIdx.x & 63;
  const int idx = bidx[tok];
  const u16* base = qkv + (size_t)tok * 3072;
  const float QS = SCALE * LOG2E;

  for (int h = w; h < 16; h += 4) {
    float x0 = bf2f(base[h * 128 + 2 * lane]);
    float x1 = bf2f(base[h * 128 + 2 * lane + 1]);
    float ss = x0 * x0 + x1 * x1;
#pragma unroll
    for (int o = 32; o; o >>= 1) ss += __shfl_xor(ss, o);
    float rn = rsqrtf(ss * (1.f / 128.f) + 1e-6f) * QS;
    size_t ob = ((size_t)(b * 16 + h) * 2048 + s) * 160;
    u32 pk = (u32)f2bf(x0 * rn * qnw[2 * lane]) |
             ((u32)f2bf(x1 * rn * qnw[2 * lane + 1]) << 16);
    *reinterpret_cast<u32*>(&qcat[ob + 2 * lane]) = pk;
    if (lane < 32) {
      float e = qbe_t[idx * 512 + h * 32 + lane];
      float s2 = e * e;
#pragma unroll
      for (int o = 16; o; o >>= 1) s2 += __shfl_xor(s2, o);
      qcat[ob + 128 + lane] = f2bf(e * rsqrtf(s2 * (1.f / 32.f) + 1e-6f) * qbn[lane] * QS);
    }
  }
  {
    const int kv = w;
    float x0 = bf2f(base[2048 + kv * 128 + 2 * lane]);
    float x1 = bf2f(base[2048 + kv * 128 + 2 * lane + 1]);
    float ss = x0 * x0 + x1 * x1;
#pragma unroll
    for (int o = 32; o; o >>= 1) ss += __shfl_xor(ss, o);
    float rn = rsqrtf(ss * (1.f / 128.f) + 1e-6f);
    size_t ob = ((size_t)(b * 4 + kv) * 2048 + s) * 160;
    u32 pk = (u32)f2bf(x0 * rn * knw[2 * lane]) |
             ((u32)f2bf(x1 * rn * knw[2 * lane + 1]) << 16);
    *reinterpret_cast<u32*>(&kcat[ob + 2 * lane]) = pk;
    if (lane < 32) {
      float e = kbe_t[idx * 128 + kv * 32 + lane];
      float s2 = e * e;
#pragma unroll
      for (int o = 16; o; o >>= 1) s2 += __shfl_xor(s2, o);
      kcat[ob + 128 + lane] = f2bf(e * rsqrtf(s2 * (1.f / 32.f) + 1e-6f) * kbn[lane]);
    }
    size_t vb = (size_t)(b * 4 + kv) * 128 * 2048;
    vt[vb + (size_t)lane * 2048 + s] = base[2560 + kv * 128 + lane];
    vt[vb + (size_t)(lane + 64) * 2048 + s] = base[2560 + kv * 128 + 64 + lane];
  }
}

// ---------------- flash attention v8 + balanced g-mapping (round-16 frontier) ----------------
__global__ __launch_bounds__(256, 2) void attn(const u16* __restrict__ qcat,
                                               const u16* __restrict__ kcat,
                                               const u16* __restrict__ vt,
                                               u16* __restrict__ aout) {
  __shared__ __align__(16) u16 Kls[2][10240];  // [64 rows][20 granules of 8] swizzled
  __shared__ __align__(16) u16 Vls[8192];      // V^T [128 d][8 granules of 8 keys] swizzled
  const int tid = threadIdx.x;
  const int blk = blockIdx.x;
  const int kvh = blk & 3;
  const int b = (blk >> 2) & 1;
  const int hq = (blk >> 3) & 3;
  const int gsel = blk >> 5;  // 0..15
  const int g = (gsel < 8) ? gsel : 23 - gsel;  // 0..7 then 15..8 (pairs sum to 15)
  const int h = kvh * 4 + hq;
  const int w = tid >> 6;
  const int lane = tid & 63;
  const int lg = lane >> 4, lr = lane & 15;
  const int qb_a = g * 4 + w;        // 0..63
  const int qb_b = 127 - qb_a;       // 64..127
  const int qpa = qb_a * 16 + lr;
  const int qpb = qb_b * 16 + lr;
  const int nt = 32 - g;             // tiles: uniform across the block's waves

  const u16* qpA = qcat + ((size_t)(b * 16 + h) * 2048 + qb_a * 16) * 160;
  const u16* qpB = qcat + ((size_t)(b * 16 + h) * 2048 + qb_b * 16) * 160;
  bf16x8 qfa[5], qfb[5];
#pragma unroll
  for (int c = 0; c < 5; ++c) {
    qfa[c] = ldfrag(qpA + lr * 160 + c * 32 + lg * 8);
    qfb[c] = ldfrag(qpB + lr * 160 + c * 32 + lg * 8);
  }

  const u16* kbp = kcat + (size_t)(b * 4 + kvh) * 2048 * 160;
  const u16* vbp = vt + (size_t)(b * 4 + kvh) * 128 * 2048;

  auto stageK = [&](int buf, int kt) {
    const u16* ksrc = kbp + (size_t)kt * (64 * 160);
#pragma unroll
    for (int it = 0; it < 5; ++it) {
      int G = it * 256 + tid;
      int r = G / 20, p = G - r * 20;
      int gs = p ^ ((r >> 1) & 3);
      gld16(ksrc + r * 160 + gs * 8, &Kls[buf][G * 8]);
    }
  };
  auto stageV = [&](int kt) {
    const u16* vsrc = vbp + kt * 64;
#pragma unroll
    for (int it = 0; it < 4; ++it) {
      int G = it * 256 + tid;
      int r = G >> 3, p = G & 7;
      int gs = p ^ (r & 7);
      gld16(vsrc + (size_t)r * 2048 + gs * 8, &Vls[G * 8]);
    }
  };

  float ma = -INFINITY, la = 0.f, mb = -INFINITY, lb = 0.f;
  f32x4 acc_a[8] = {}, acc_b[8] = {};

  stageK(0, 0);
  stageV(0);
  __syncthreads();

  for (int kt = 0; kt < nt; ++kt) {
    const int buf = kt & 1;
    const bool aact = (kt <= g);
    if (kt + 1 < nt) stageK(buf ^ 1, kt + 1);

    f32x4 sa[4] = {}, sb[4] = {};
#pragma unroll
    for (int c = 0; c < 5; ++c) {
      bf16x8 kf[4];
#pragma unroll
      for (int i = 0; i < 4; ++i) {
        int r = i * 16 + lr;
        int p = (c * 4 + lg) ^ ((r >> 1) & 3);
        kf[i] = ldfrag(&Kls[buf][(r * 20 + p) * 8]);
      }
#pragma unroll
      for (int i = 0; i < 4; ++i)
        sb[i] = __builtin_amdgcn_mfma_f32_16x16x32_bf16(kf[i], qfb[c], sb[i], 0, 0, 0);
      if (aact)
#pragma unroll
        for (int i = 0; i < 4; ++i)
          sa[i] = __builtin_amdgcn_mfma_f32_16x16x32_bf16(kf[i], qfa[c], sa[i], 0, 0, 0);
    }

    // --- softmax in exp2 domain (q pre-scaled by SCALE*log2e), defer-max THR=8 ---
    s16x4 pka[4], pkb[4];
    auto soft = [&](f32x4 (&st)[4], float& mm, float& ls, f32x4 (&ac)[8], s16x4 (&pk)[4],
                    bool masked, int qpos) {
      float vmax = -INFINITY;
#pragma unroll
      for (int i = 0; i < 4; ++i)
#pragma unroll
        for (int r = 0; r < 4; ++r) {
          float v = st[i][r];
          if (masked && (kt * 64 + i * 16 + 4 * lg + r > qpos)) v = -INFINITY;
          st[i][r] = v;
          vmax = fmaxf(vmax, v);
        }
      vmax = fmaxf(vmax, __shfl_xor(vmax, 16));
      vmax = fmaxf(vmax, __shfl_xor(vmax, 32));
      bool skip = __all(vmax <= mm + 8.f);  // defer-max: P bounded by 2^8
      float mn = skip ? mm : fmaxf(mm, vmax);
      float rs = 0.f;
#pragma unroll
      for (int i = 0; i < 4; ++i)
#pragma unroll
        for (int r = 0; r < 4; ++r) {
          float p = exp2f(st[i][r] - mn);
          st[i][r] = p;
          rs += p;
        }
      rs += __shfl_xor(rs, 16);
      rs += __shfl_xor(rs, 32);
      if (skip) {
        ls += rs;
      } else {
        float corr = exp2f(mm - mn);
        ls = ls * corr + rs;
        mm = mn;
        float c4[4];
#pragma unroll
        for (int r = 0; r < 4; ++r) c4[r] = __shfl(corr, 4 * lg + r);
#pragma unroll
        for (int dt = 0; dt < 8; ++dt)
#pragma unroll
          for (int r = 0; r < 4; ++r) ac[dt][r] *= c4[r];
      }
#pragma unroll
      for (int i = 0; i < 4; ++i) {
        pk[i][0] = (short)f2bf_fast(st[i][0]);
        pk[i][1] = (short)f2bf_fast(st[i][1]);
        pk[i][2] = (short)f2bf_fast(st[i][2]);
        pk[i][3] = (short)f2bf_fast(st[i][3]);
      }
    };
    soft(sb, mb, lb, acc_b, pkb, kt == nt - 1, qpb);
    if (aact) soft(sa, ma, la, acc_a, pka, kt == g, qpa);

    __syncthreads();  // #1: V(kt) staged by all waves is complete

#pragma unroll
    for (int ks = 0; ks < 4; ++ks) {
      s16x4 vf[8];
#pragma unroll
      for (int dt = 0; dt < 8; ++dt) {
        int r = dt * 16 + lr;
        int p = (ks * 2 + (lg >> 1)) ^ (r & 7);
        vf[dt] = *reinterpret_cast<const s16x4*>(&Vls[(r * 8 + p) * 8 + (lg & 1) * 4]);
      }
#pragma unroll
      for (int dt = 0; dt < 8; ++dt) acc_b[dt] = mfma16x16(pkb[ks], vf[dt], acc_b[dt]);
      if (aact)
#pragma unroll
        for (int dt = 0; dt < 8; ++dt) acc_a[dt] = mfma16x16(pka[ks], vf[dt], acc_a[dt]);
    }

    __syncthreads();  // #2: all waves done reading Vls
    if (kt + 1 < nt) stageV(kt + 1);
  }

  float inva[4], invb[4];
#pragma unroll
  for (int r = 0; r < 4; ++r) {
    inva[r] = 1.f / __shfl(la, 4 * lg + r);
    invb[r] = 1.f / __shfl(lb, 4 * lg + r);
  }
#pragma unroll
  for (int dt = 0; dt < 8; ++dt)
#pragma unroll
    for (int r = 0; r < 4; ++r) {
      int rowa = qb_a * 16 + 4 * lg + r;
      int rowb = qb_b * 16 + 4 * lg + r;
      aout[((size_t)(b * 2048 + rowa) * 16 + h) * 128 + dt * 16 + lr] =
          f2bf(acc_a[dt][r] * inva[r]);
      aout[((size_t)(b * 2048 + rowb) * 16 + h) * 128 + dt * 16 + lr] =
          f2bf(acc_b[dt][r] * invb[r]);
    }
}

extern "C" void kernel_launch(void* const* d_in, const int* in_sizes, int n_in,
                              void* d_out, int out_size, void* d_ws, size_t ws_size,
                              hipStream_t stream) {
  const float* hs = (const float*)d_in[0];
  const int* bidx = (const int*)d_in[1];
  const float* qw = (const float*)d_in[2];
  const float* kw = (const float*)d_in[3];
  const float* vw = (const float*)d_in[4];
  const float* ow = (const float*)d_in[5];
  const float* qnw = (const float*)d_in[6];
  const float* knw = (const float*)d_in[7];
  const float* qbe_t = (const float*)d_in[8];
  const float* kbe_t = (const float*)d_in[9];
  const float* qbn = (const float*)d_in[10];
  const float* kbn = (const float*)d_in[11];

  u16* ws = (u16*)d_ws;
  u16* hs_bf = ws;                       // 4096*2048
  u16* wqkv = hs_bf + 8388608;           // 3072*2048
  u16* ow_bf = wqkv + 6291456;           // 2048*2048
  u16* qkv = ow_bf + 4194304;            // 4096*3072
  u16* qcat = qkv + 12582912;            // 2*16*2048*160
  u16* kcat = qcat + 10485760;           // 2*4*2048*160
  u16* vt = kcat + 2621440;              // 2*4*128*2048
  u16* attn_o = vt + 2097152;            // 4096*2048

  conv_all<<<4608, 256, 0, stream>>>(hs, qw, kw, vw, ow, hs_bf, wqkv, ow_bf);

  gemm_bt<1><<<dim3((4096 / 128) * (3072 / 128)), 256, 0, stream>>>(
      hs_bf, wqkv, (void*)qkv, 4096, 3072, 2048);

  postproc<<<4096, 256, 0, stream>>>(qkv, bidx, qnw, knw, qbe_t, kbe_t, qbn, kbn,
                                     qcat, kcat, vt);

  attn<<<512, 256, 0, stream>>>(qcat, kcat, vt, attn_o);

  gemm_bt<0><<<dim3((4096 / 128) * (2048 / 128)), 256, 0, stream>>>(
      attn_o, ow_bf, (void*)d_out, 4096, 2048, 2048);
}

// Round 19
// 217.578 us; speedup vs baseline: 1.2406x; 1.0254x over previous
//
#include <hip/hip_runtime.h>

typedef unsigned short u16;
typedef unsigned int u32;
typedef __bf16 bf16x8 __attribute__((ext_vector_type(8)));
typedef __bf16 b16x4 __attribute__((ext_vector_type(4)));
typedef short s16x4 __attribute__((ext_vector_type(4)));
typedef float f32x4 __attribute__((ext_vector_type(4)));

#define SCALE 0.07905694150420949f   // (128+32)^-0.5
#define LOG2E 1.4426950408889634f

__device__ __forceinline__ float bf2f(u16 h) { return __uint_as_float(((u32)h) << 16); }
__device__ __forceinline__ u16 f2bf(float f) {  // RNE-ish
  u32 u = __float_as_uint(f);
  u += 0x7fffu + ((u >> 16) & 1u);
  return (u16)(u >> 16);
}
__device__ __forceinline__ u16 f2bf_fast(float f) {  // round-half-up, for attention P
  return (u16)((__float_as_uint(f) + 0x8000u) >> 16);
}
__device__ __forceinline__ bf16x8 ldfrag(const u16* p) {
  int4 t = *reinterpret_cast<const int4*>(p);
  return __builtin_bit_cast(bf16x8, t);
}

// 16x16x16 bf16 MFMA (A,B = 4 bf16 per lane, k = 4*(lane>>4)+j)
__device__ __forceinline__ f32x4 mfma16x16(s16x4 a, s16x4 b, f32x4 c) {
#if __has_builtin(__builtin_amdgcn_mfma_f32_16x16x16bf16_1k)
  return __builtin_amdgcn_mfma_f32_16x16x16bf16_1k(a, b, c, 0, 0, 0);
#elif __has_builtin(__builtin_amdgcn_mfma_f32_16x16x16_bf16)
  return __builtin_amdgcn_mfma_f32_16x16x16_bf16(__builtin_bit_cast(b16x4, a),
                                                 __builtin_bit_cast(b16x4, b), c, 0, 0, 0);
#else
  asm volatile("s_nop 2\n\tv_mfma_f32_16x16x16_bf16 %0, %1, %2, %0"
               : "+v"(c) : "v"(a), "v"(b));
  return c;
#endif
}

// async global->LDS, 16B per lane (dest = wave-uniform base + lane*16)
__device__ __forceinline__ void gld16(const u16* g, u16* l) {
  __builtin_amdgcn_global_load_lds((const __attribute__((address_space(1))) u32*)(const void*)g,
                                   (__attribute__((address_space(3))) u32*)(void*)l, 16, 0, 0);
}

// ---------------- merged f32 -> bf16 converts (one launch) ----------------
__global__ void conv_all(const float* __restrict__ hs, const float* __restrict__ qw,
                         const float* __restrict__ kw, const float* __restrict__ vw,
                         const float* __restrict__ ow, u16* __restrict__ hs_bf,
                         u16* __restrict__ wqkv, u16* __restrict__ ow_bf) {
  const int total = 4718592;
  for (int i = blockIdx.x * blockDim.x + threadIdx.x; i < total; i += gridDim.x * blockDim.x) {
    const float* src;
    u16* dst;
    int j = i;
    if (j < 2097152) {
      src = hs; dst = hs_bf;
    } else if (j < 3145728) {
      j -= 2097152; src = qw; dst = wqkv;
    } else if (j < 3407872) {
      j -= 3145728; src = kw; dst = wqkv + 4194304;
    } else if (j < 3670016) {
      j -= 3407872; src = vw; dst = wqkv + 5242880;
    } else {
      j -= 3670016; src = ow; dst = ow_bf;
    }
    float4 v = reinterpret_cast<const float4*>(src)[j];
    ushort4 o = {f2bf(v.x), f2bf(v.y), f2bf(v.z), f2bf(v.w)};
    reinterpret_cast<ushort4*>(dst)[j] = o;
  }
}

// ---------------- GEMM: 128x128, counted vmcnt(8), 2-deep (round-10 proven loop) ----------------
// MODE 0: plain f32 C-write (O-proj).
// MODE 2: fused QKV epilogue — per-head RMSNorm (cols of a block == exactly one head),
//         behavior-embed norm+concat, V transpose. Writes qcat/kcat/vt from f32 acc.
template <int MODE>
__global__ __launch_bounds__(256, 2) void gemm_bt(
    const u16* __restrict__ A, const u16* __restrict__ Bw, void* __restrict__ Cv,
    int M, int N, int K,
    const int* __restrict__ bidx, const float* __restrict__ qnw, const float* __restrict__ knw,
    const float* __restrict__ qbe_t, const float* __restrict__ kbe_t,
    const float* __restrict__ qbn, const float* __restrict__ kbn,
    u16* __restrict__ qcat, u16* __restrict__ kcat, u16* __restrict__ vt) {
  __shared__ __align__(16) u16 As[2][8192];
  __shared__ __align__(16) u16 Bs[2][8192];
  __shared__ float red[128][2];
  const int tid = threadIdx.x;
  const int nbn = N >> 7;
  const int cpx = gridDim.x >> 3;
  const int swz = (blockIdx.x & 7) * cpx + (blockIdx.x >> 3);
  const int bm = swz / nbn, bn = swz % nbn;
  const int row0 = bm << 7, col0 = bn << 7;
  const int lane = tid & 63, w = tid >> 6;
  const int lg = lane >> 4, lr = lane & 15;
  const int wr = w >> 1, wc = w & 1;
  const int nt = K >> 6;

  auto stage = [&](int slot, int t) {
    const size_t k0 = (size_t)t << 6;
#pragma unroll
    for (int it = 0; it < 4; ++it) {
      int G = it * 256 + tid;
      int r = G >> 3, p = G & 7;
      int gs = p ^ (r & 7);
      gld16(&A[(size_t)(row0 + r) * K + k0 + gs * 8], &As[slot][(size_t)G * 8]);
      gld16(&Bw[(size_t)(col0 + r) * K + k0 + gs * 8], &Bs[slot][(size_t)G * 8]);
    }
  };

  f32x4 acc[4][4] = {};
  stage(0, 0);
  if (nt > 1) stage(1, 1);

  for (int t = 0; t < nt; ++t) {
    const int slot = t & 1;
    if (t + 1 < nt) {
      asm volatile("s_waitcnt vmcnt(8)" ::: "memory");
    } else {
      asm volatile("s_waitcnt vmcnt(0)" ::: "memory");
    }
    __builtin_amdgcn_s_barrier();
    __builtin_amdgcn_sched_barrier(0);
#pragma unroll
    for (int kk = 0; kk < 2; ++kk) {
      bf16x8 af[4], bv[4];
#pragma unroll
      for (int m = 0; m < 4; ++m) {
        int r = wr * 64 + m * 16 + lr;
        int g = (kk * 4 + lg) ^ (lr & 7);
        af[m] = ldfrag(&As[slot][r * 64 + g * 8]);
      }
#pragma unroll
      for (int n = 0; n < 4; ++n) {
        int r = wc * 64 + n * 16 + lr;
        int g = (kk * 4 + lg) ^ (lr & 7);
        bv[n] = ldfrag(&Bs[slot][r * 64 + g * 8]);
      }
#pragma unroll
      for (int m = 0; m < 4; ++m)
#pragma unroll
        for (int n = 0; n < 4; ++n)
          acc[m][n] = __builtin_amdgcn_mfma_f32_16x16x32_bf16(af[m], bv[n], acc[m][n], 0, 0, 0);
    }
    __builtin_amdgcn_sched_barrier(0);
    __builtin_amdgcn_s_barrier();
    if (t + 2 < nt) stage(slot, t + 2);
  }

  if (MODE == 0) {
#pragma unroll
    for (int m = 0; m < 4; ++m)
#pragma unroll
      for (int n = 0; n < 4; ++n)
#pragma unroll
        for (int r = 0; r < 4; ++r) {
          int row = row0 + wr * 64 + m * 16 + lg * 4 + r;
          int col = col0 + wc * 64 + n * 16 + lr;
          ((float*)Cv)[(size_t)row * N + col] = acc[m][n][r];
        }
    return;
  }

  // ---------------- fused QKV epilogue (MODE 2) ----------------
  const int cb = col0 >> 7;  // 0..15 q-head, 16..19 k-head, 20..23 v-head
  const float QS = SCALE * LOG2E;

  if (cb < 20) {
    // per-row sum of x^2 over this wave's 64 cols
    float part[4][4];
#pragma unroll
    for (int m = 0; m < 4; ++m)
#pragma unroll
      for (int r = 0; r < 4; ++r) {
        float s = 0.f;
#pragma unroll
        for (int n = 0; n < 4; ++n) s += acc[m][n][r] * acc[m][n][r];
#pragma unroll
        for (int o = 1; o < 16; o <<= 1) s += __shfl_xor(s, o);  // reduce over lr
        part[m][r] = s;
      }
    if (lr == 0) {
#pragma unroll
      for (int m = 0; m < 4; ++m)
#pragma unroll
        for (int r = 0; r < 4; ++r) red[wr * 64 + m * 16 + lg * 4 + r][wc] = part[m][r];
    }
    __syncthreads();

    const bool isq = (cb < 16);
    const float* nw = isq ? qnw : knw;
    u16* outp = isq ? qcat : kcat;
    const int hb = isq ? (16 * 2048) : (4 * 2048);  // rows per batch in out tensor
    const int hh = isq ? cb : (cb - 16);
#pragma unroll
    for (int m = 0; m < 4; ++m)
#pragma unroll
      for (int r = 0; r < 4; ++r) {
        int rl = wr * 64 + m * 16 + lg * 4 + r;
        float ss = red[rl][0] + red[rl][1];
        float rn = rsqrtf(ss * (1.f / 128.f) + 1e-6f) * (isq ? QS : 1.f);
        int token = row0 + rl;
        int bb = token >> 11, s = token & 2047;
        size_t ob = ((size_t)(bb * hb) + (size_t)hh * 2048 + s) * 160;
#pragma unroll
        for (int n = 0; n < 4; ++n) {
          int d = wc * 64 + n * 16 + lr;
          outp[ob + d] = f2bf(acc[m][n][r] * rn * nw[d]);
        }
      }
    // behavior-embed norm + concat: one token per thread (tokens 0..127)
    if (tid < 128) {
      int token = row0 + tid;
      int bb = token >> 11, s = token & 2047;
      int idx = bidx[token];
      const float* ep;
      const float* bw;
      float qs;
      size_t ob;
      if (isq) {
        ep = qbe_t + idx * 512 + hh * 32;
        bw = qbn;
        qs = QS;
        ob = ((size_t)(bb * 16 + hh) * 2048 + s) * 160 + 128;
      } else {
        ep = kbe_t + idx * 128 + hh * 32;
        bw = kbn;
        qs = 1.f;
        ob = ((size_t)(bb * 4 + hh) * 2048 + s) * 160 + 128;
      }
      float ss = 0.f;
#pragma unroll
      for (int e = 0; e < 32; ++e) {
        float v = ep[e];
        ss += v * v;
      }
      float rn = rsqrtf(ss * (1.f / 32.f) + 1e-6f) * qs;
#pragma unroll
      for (int e = 0; e < 32; ++e) outp[ob + e] = f2bf(ep[e] * rn * bw[e]);
    }
  } else {
    // v-head: plain transpose write vt[(bb*4+kv)*128 + d][s]
    const int kv = cb - 20;
#pragma unroll
    for (int m = 0; m < 4; ++m)
#pragma unroll
      for (int r = 0; r < 4; ++r) {
        int token = row0 + wr * 64 + m * 16 + lg * 4 + r;
        int bb = token >> 11, s = token & 2047;
#pragma unroll
        for (int n = 0; n < 4; ++n) {
          int d = wc * 64 + n * 16 + lr;
          vt[((size_t)(bb * 4 + kv) * 128 + d) * 2048 + s] = f2bf(acc[m][n][r]);
        }
      }
  }
}

// ---------------- flash attention v8 + balanced g-mapping (round-16 frontier) ----------------
__global__ __launch_bounds__(256, 2) void attn(const u16* __restrict__ qcat,
                                               const u16* __restrict__ kcat,
                                               const u16* __restrict__ vt,
                                               u16* __restrict__ aout) {
  __shared__ __align__(16) u16 Kls[2][10240];  // [64 rows][20 granules of 8] swizzled
  __shared__ __align__(16) u16 Vls[8192];      // V^T [128 d][8 granules of 8 keys] swizzled
  const int tid = threadIdx.x;
  const int blk = blockIdx.x;
  const int kvh = blk & 3;
  const int b = (blk >> 2) & 1;
  const int hq = (blk >> 3) & 3;
  const int gsel = blk >> 5;  // 0..15
  const int g = (gsel < 8) ? gsel : 23 - gsel;  // 0..7 then 15..8 (pairs sum to 15)
  const int h = kvh * 4 + hq;
  const int w = tid >> 6;
  const int lane = tid & 63;
  const int lg = lane >> 4, lr = lane & 15;
  const int qb_a = g * 4 + w;        // 0..63
  const int qb_b = 127 - qb_a;       // 64..127
  const int qpa = qb_a * 16 + lr;
  const int qpb = qb_b * 16 + lr;
  const int nt = 32 - g;             // tiles: uniform across the block's waves

  const u16* qpA = qcat + ((size_t)(b * 16 + h) * 2048 + qb_a * 16) * 160;
  const u16* qpB = qcat + ((size_t)(b * 16 + h) * 2048 + qb_b * 16) * 160;
  bf16x8 qfa[5], qfb[5];
#pragma unroll
  for (int c = 0; c < 5; ++c) {
    qfa[c] = ldfrag(qpA + lr * 160 + c * 32 + lg * 8);
    qfb[c] = ldfrag(qpB + lr * 160 + c * 32 + lg * 8);
  }

  const u16* kbp = kcat + (size_t)(b * 4 + kvh) * 2048 * 160;
  const u16* vbp = vt + (size_t)(b * 4 + kvh) * 128 * 2048;

  auto stageK = [&](int buf, int kt) {
    const u16* ksrc = kbp + (size_t)kt * (64 * 160);
#pragma unroll
    for (int it = 0; it < 5; ++it) {
      int G = it * 256 + tid;
      int r = G / 20, p = G - r * 20;
      int gs = p ^ ((r >> 1) & 3);
      gld16(ksrc + r * 160 + gs * 8, &Kls[buf][G * 8]);
    }
  };
  auto stageV = [&](int kt) {
    const u16* vsrc = vbp + kt * 64;
#pragma unroll
    for (int it = 0; it < 4; ++it) {
      int G = it * 256 + tid;
      int r = G >> 3, p = G & 7;
      int gs = p ^ (r & 7);
      gld16(vsrc + (size_t)r * 2048 + gs * 8, &Vls[G * 8]);
    }
  };

  float ma = -INFINITY, la = 0.f, mb = -INFINITY, lb = 0.f;
  f32x4 acc_a[8] = {}, acc_b[8] = {};

  stageK(0, 0);
  stageV(0);
  __syncthreads();

  for (int kt = 0; kt < nt; ++kt) {
    const int buf = kt & 1;
    const bool aact = (kt <= g);
    if (kt + 1 < nt) stageK(buf ^ 1, kt + 1);

    f32x4 sa[4] = {}, sb[4] = {};
#pragma unroll
    for (int c = 0; c < 5; ++c) {
      bf16x8 kf[4];
#pragma unroll
      for (int i = 0; i < 4; ++i) {
        int r = i * 16 + lr;
        int p = (c * 4 + lg) ^ ((r >> 1) & 3);
        kf[i] = ldfrag(&Kls[buf][(r * 20 + p) * 8]);
      }
#pragma unroll
      for (int i = 0; i < 4; ++i)
        sb[i] = __builtin_amdgcn_mfma_f32_16x16x32_bf16(kf[i], qfb[c], sb[i], 0, 0, 0);
      if (aact)
#pragma unroll
        for (int i = 0; i < 4; ++i)
          sa[i] = __builtin_amdgcn_mfma_f32_16x16x32_bf16(kf[i], qfa[c], sa[i], 0, 0, 0);
    }

    // --- softmax in exp2 domain (q pre-scaled by SCALE*log2e), defer-max THR=8 ---
    s16x4 pka[4], pkb[4];
    auto soft = [&](f32x4 (&st)[4], float& mm, float& ls, f32x4 (&ac)[8], s16x4 (&pk)[4],
                    bool masked, int qpos) {
      float vmax = -INFINITY;
#pragma unroll
      for (int i = 0; i < 4; ++i)
#pragma unroll
        for (int r = 0; r < 4; ++r) {
          float v = st[i][r];
          if (masked && (kt * 64 + i * 16 + 4 * lg + r > qpos)) v = -INFINITY;
          st[i][r] = v;
          vmax = fmaxf(vmax, v);
        }
      vmax = fmaxf(vmax, __shfl_xor(vmax, 16));
      vmax = fmaxf(vmax, __shfl_xor(vmax, 32));
      bool skip = __all(vmax <= mm + 8.f);  // defer-max: P bounded by 2^8
      float mn = skip ? mm : fmaxf(mm, vmax);
      float rs = 0.f;
#pragma unroll
      for (int i = 0; i < 4; ++i)
#pragma unroll
        for (int r = 0; r < 4; ++r) {
          float p = exp2f(st[i][r] - mn);
          st[i][r] = p;
          rs += p;
        }
      rs += __shfl_xor(rs, 16);
      rs += __shfl_xor(rs, 32);
      if (skip) {
        ls += rs;
      } else {
        float corr = exp2f(mm - mn);
        ls = ls * corr + rs;
        mm = mn;
        float c4[4];
#pragma unroll
        for (int r = 0; r < 4; ++r) c4[r] = __shfl(corr, 4 * lg + r);
#pragma unroll
        for (int dt = 0; dt < 8; ++dt)
#pragma unroll
          for (int r = 0; r < 4; ++r) ac[dt][r] *= c4[r];
      }
#pragma unroll
      for (int i = 0; i < 4; ++i) {
        pk[i][0] = (short)f2bf_fast(st[i][0]);
        pk[i][1] = (short)f2bf_fast(st[i][1]);
        pk[i][2] = (short)f2bf_fast(st[i][2]);
        pk[i][3] = (short)f2bf_fast(st[i][3]);
      }
    };
    soft(sb, mb, lb, acc_b, pkb, kt == nt - 1, qpb);
    if (aact) soft(sa, ma, la, acc_a, pka, kt == g, qpa);

    __syncthreads();  // #1: V(kt) staged by all waves is complete

#pragma unroll
    for (int ks = 0; ks < 4; ++ks) {
      s16x4 vf[8];
#pragma unroll
      for (int dt = 0; dt < 8; ++dt) {
        int r = dt * 16 + lr;
        int p = (ks * 2 + (lg >> 1)) ^ (r & 7);
        vf[dt] = *reinterpret_cast<const s16x4*>(&Vls[(r * 8 + p) * 8 + (lg & 1) * 4]);
      }
#pragma unroll
      for (int dt = 0; dt < 8; ++dt) acc_b[dt] = mfma16x16(pkb[ks], vf[dt], acc_b[dt]);
      if (aact)
#pragma unroll
        for (int dt = 0; dt < 8; ++dt) acc_a[dt] = mfma16x16(pka[ks], vf[dt], acc_a[dt]);
    }

    __syncthreads();  // #2: all waves done reading Vls
    if (kt + 1 < nt) stageV(kt + 1);
  }

  float inva[4], invb[4];
#pragma unroll
  for (int r = 0; r < 4; ++r) {
    inva[r] = 1.f / __shfl(la, 4 * lg + r);
    invb[r] = 1.f / __shfl(lb, 4 * lg + r);
  }
#pragma unroll
  for (int dt = 0; dt < 8; ++dt)
#pragma unroll
    for (int r = 0; r < 4; ++r) {
      int rowa = qb_a * 16 + 4 * lg + r;
      int rowb = qb_b * 16 + 4 * lg + r;
      aout[((size_t)(b * 2048 + rowa) * 16 + h) * 128 + dt * 16 + lr] =
          f2bf(acc_a[dt][r] * inva[r]);
      aout[((size_t)(b * 2048 + rowb) * 16 + h) * 128 + dt * 16 + lr] =
          f2bf(acc_b[dt][r] * invb[r]);
    }
}

extern "C" void kernel_launch(void* const* d_in, const int* in_sizes, int n_in,
                              void* d_out, int out_size, void* d_ws, size_t ws_size,
                              hipStream_t stream) {
  const float* hs = (const float*)d_in[0];
  const int* bidx = (const int*)d_in[1];
  const float* qw = (const float*)d_in[2];
  const float* kw = (const float*)d_in[3];
  const float* vw = (const float*)d_in[4];
  const float* ow = (const float*)d_in[5];
  const float* qnw = (const float*)d_in[6];
  const float* knw = (const float*)d_in[7];
  const float* qbe_t = (const float*)d_in[8];
  const float* kbe_t = (const float*)d_in[9];
  const float* qbn = (const float*)d_in[10];
  const float* kbn = (const float*)d_in[11];

  u16* ws = (u16*)d_ws;
  u16* hs_bf = ws;                       // 4096*2048
  u16* wqkv = hs_bf + 8388608;           // 3072*2048
  u16* ow_bf = wqkv + 6291456;           // 2048*2048
  u16* qkv = ow_bf + 4194304;            // (unused after fusion; kept for layout stability)
  u16* qcat = qkv + 12582912;            // 2*16*2048*160
  u16* kcat = qcat + 10485760;           // 2*4*2048*160
  u16* vt = kcat + 2621440;              // 2*4*128*2048
  u16* attn_o = vt + 2097152;            // 4096*2048

  conv_all<<<4608, 256, 0, stream>>>(hs, qw, kw, vw, ow, hs_bf, wqkv, ow_bf);

  // fused QKV GEMM + per-head RMSNorm + behavior embed + V transpose
  gemm_bt<2><<<dim3((4096 / 128) * (3072 / 128)), 256, 0, stream>>>(
      hs_bf, wqkv, nullptr, 4096, 3072, 2048,
      bidx, qnw, knw, qbe_t, kbe_t, qbn, kbn, qcat, kcat, vt);

  attn<<<512, 256, 0, stream>>>(qcat, kcat, vt, attn_o);

  gemm_bt<0><<<dim3((4096 / 128) * (2048 / 128)), 256, 0, stream>>>(
      attn_o, ow_bf, (void*)d_out, 4096, 2048, 2048,
      nullptr, nullptr, nullptr, nullptr, nullptr, nullptr, nullptr,
      nullptr, nullptr, nullptr);
}

// Round 20
// 216.542 us; speedup vs baseline: 1.2465x; 1.0048x over previous
//
#include <hip/hip_runtime.h>

typedef unsigned short u16;
typedef unsigned int u32;
typedef __bf16 bf16x8 __attribute__((ext_vector_type(8)));
typedef __bf16 b16x4 __attribute__((ext_vector_type(4)));
typedef short s16x4 __attribute__((ext_vector_type(4)));
typedef float f32x4 __attribute__((ext_vector_type(4)));

#define SCALE 0.07905694150420949f   // (128+32)^-0.5
#define LOG2E 1.4426950408889634f

__device__ __forceinline__ float bf2f(u16 h) { return __uint_as_float(((u32)h) << 16); }
__device__ __forceinline__ u16 f2bf(float f) {  // RNE-ish
  u32 u = __float_as_uint(f);
  u += 0x7fffu + ((u >> 16) & 1u);
  return (u16)(u >> 16);
}
__device__ __forceinline__ u16 f2bf_fast(float f) {  // round-half-up, for attention P
  return (u16)((__float_as_uint(f) + 0x8000u) >> 16);
}
__device__ __forceinline__ bf16x8 ldfrag(const u16* p) {
  int4 t = *reinterpret_cast<const int4*>(p);
  return __builtin_bit_cast(bf16x8, t);
}

// 16x16x16 bf16 MFMA (A,B = 4 bf16 per lane, k = 4*(lane>>4)+j)
__device__ __forceinline__ f32x4 mfma16x16(s16x4 a, s16x4 b, f32x4 c) {
#if __has_builtin(__builtin_amdgcn_mfma_f32_16x16x16bf16_1k)
  return __builtin_amdgcn_mfma_f32_16x16x16bf16_1k(a, b, c, 0, 0, 0);
#elif __has_builtin(__builtin_amdgcn_mfma_f32_16x16x16_bf16)
  return __builtin_amdgcn_mfma_f32_16x16x16_bf16(__builtin_bit_cast(b16x4, a),
                                                 __builtin_bit_cast(b16x4, b), c, 0, 0, 0);
#else
  asm volatile("s_nop 2\n\tv_mfma_f32_16x16x16_bf16 %0, %1, %2, %0"
               : "+v"(c) : "v"(a), "v"(b));
  return c;
#endif
}

// async global->LDS, 16B per lane (dest = wave-uniform base + lane*16)
__device__ __forceinline__ void gld16(const u16* g, u16* l) {
  __builtin_amdgcn_global_load_lds((const __attribute__((address_space(1))) u32*)(const void*)g,
                                   (__attribute__((address_space(3))) u32*)(void*)l, 16, 0, 0);
}

// ---------------- merged f32 -> bf16 converts (one launch) ----------------
__global__ void conv_all(const float* __restrict__ hs, const float* __restrict__ qw,
                         const float* __restrict__ kw, const float* __restrict__ vw,
                         const float* __restrict__ ow, u16* __restrict__ hs_bf,
                         u16* __restrict__ wqkv, u16* __restrict__ ow_bf) {
  const int total = 4718592;
  for (int i = blockIdx.x * blockDim.x + threadIdx.x; i < total; i += gridDim.x * blockDim.x) {
    const float* src;
    u16* dst;
    int j = i;
    if (j < 2097152) {
      src = hs; dst = hs_bf;
    } else if (j < 3145728) {
      j -= 2097152; src = qw; dst = wqkv;
    } else if (j < 3407872) {
      j -= 3145728; src = kw; dst = wqkv + 4194304;
    } else if (j < 3670016) {
      j -= 3407872; src = vw; dst = wqkv + 5242880;
    } else {
      j -= 3670016; src = ow; dst = ow_bf;
    }
    float4 v = reinterpret_cast<const float4*>(src)[j];
    ushort4 o = {f2bf(v.x), f2bf(v.y), f2bf(v.z), f2bf(v.w)};
    reinterpret_cast<ushort4*>(dst)[j] = o;
  }
}

// ---------------- GEMM: 128x128, counted vmcnt(8), 2-deep (round-10 proven loop) ----------------
// MODE 0: plain f32 C-write (O-proj).
// MODE 2: fused QKV epilogue — per-head RMSNorm, behavior-embed norm+concat, V transpose.
template <int MODE>
__global__ __launch_bounds__(256, 2) void gemm_bt(
    const u16* __restrict__ A, const u16* __restrict__ Bw, void* __restrict__ Cv,
    int M, int N, int K,
    const int* __restrict__ bidx, const float* __restrict__ qnw, const float* __restrict__ knw,
    const float* __restrict__ qbe_t, const float* __restrict__ kbe_t,
    const float* __restrict__ qbn, const float* __restrict__ kbn,
    u16* __restrict__ qcat, u16* __restrict__ kcat, u16* __restrict__ vt) {
  __shared__ __align__(16) u16 As[2][8192];
  __shared__ __align__(16) u16 Bs[2][8192];
  __shared__ float red[(MODE == 2) ? 128 : 1][2];
  const int tid = threadIdx.x;
  const int nbn = N >> 7;
  const int cpx = gridDim.x >> 3;
  const int swz = (blockIdx.x & 7) * cpx + (blockIdx.x >> 3);
  const int bm = swz / nbn, bn = swz % nbn;
  const int row0 = bm << 7, col0 = bn << 7;
  const int lane = tid & 63, w = tid >> 6;
  const int lg = lane >> 4, lr = lane & 15;
  const int wr = w >> 1, wc = w & 1;
  const int nt = K >> 6;

  auto stage = [&](int slot, int t) {
    const size_t k0 = (size_t)t << 6;
#pragma unroll
    for (int it = 0; it < 4; ++it) {
      int G = it * 256 + tid;
      int r = G >> 3, p = G & 7;
      int gs = p ^ (r & 7);
      gld16(&A[(size_t)(row0 + r) * K + k0 + gs * 8], &As[slot][(size_t)G * 8]);
      gld16(&Bw[(size_t)(col0 + r) * K + k0 + gs * 8], &Bs[slot][(size_t)G * 8]);
    }
  };

  f32x4 acc[4][4] = {};
  stage(0, 0);
  if (nt > 1) stage(1, 1);

  for (int t = 0; t < nt; ++t) {
    const int slot = t & 1;
    if (t + 1 < nt) {
      asm volatile("s_waitcnt vmcnt(8)" ::: "memory");
    } else {
      asm volatile("s_waitcnt vmcnt(0)" ::: "memory");
    }
    __builtin_amdgcn_s_barrier();
    __builtin_amdgcn_sched_barrier(0);
#pragma unroll
    for (int kk = 0; kk < 2; ++kk) {
      bf16x8 af[4], bv[4];
#pragma unroll
      for (int m = 0; m < 4; ++m) {
        int r = wr * 64 + m * 16 + lr;
        int g = (kk * 4 + lg) ^ (lr & 7);
        af[m] = ldfrag(&As[slot][r * 64 + g * 8]);
      }
#pragma unroll
      for (int n = 0; n < 4; ++n) {
        int r = wc * 64 + n * 16 + lr;
        int g = (kk * 4 + lg) ^ (lr & 7);
        bv[n] = ldfrag(&Bs[slot][r * 64 + g * 8]);
      }
#pragma unroll
      for (int m = 0; m < 4; ++m)
#pragma unroll
        for (int n = 0; n < 4; ++n)
          acc[m][n] = __builtin_amdgcn_mfma_f32_16x16x32_bf16(af[m], bv[n], acc[m][n], 0, 0, 0);
    }
    __builtin_amdgcn_sched_barrier(0);
    __builtin_amdgcn_s_barrier();
    if (t + 2 < nt) stage(slot, t + 2);
  }

  if (MODE == 0) {
#pragma unroll
    for (int m = 0; m < 4; ++m)
#pragma unroll
      for (int n = 0; n < 4; ++n)
#pragma unroll
        for (int r = 0; r < 4; ++r) {
          int row = row0 + wr * 64 + m * 16 + lg * 4 + r;
          int col = col0 + wc * 64 + n * 16 + lr;
          ((float*)Cv)[(size_t)row * N + col] = acc[m][n][r];
        }
    return;
  }

  // ---------------- fused QKV epilogue (MODE 2) ----------------
  const int cb = col0 >> 7;  // 0..15 q-head, 16..19 k-head, 20..23 v-head
  const float QS = SCALE * LOG2E;

  if (cb < 20) {
    float part[4][4];
#pragma unroll
    for (int m = 0; m < 4; ++m)
#pragma unroll
      for (int r = 0; r < 4; ++r) {
        float s = 0.f;
#pragma unroll
        for (int n = 0; n < 4; ++n) s += acc[m][n][r] * acc[m][n][r];
#pragma unroll
        for (int o = 1; o < 16; o <<= 1) s += __shfl_xor(s, o);  // reduce over lr
        part[m][r] = s;
      }
    if (lr == 0) {
#pragma unroll
      for (int m = 0; m < 4; ++m)
#pragma unroll
        for (int r = 0; r < 4; ++r) red[wr * 64 + m * 16 + lg * 4 + r][wc] = part[m][r];
    }
    __syncthreads();

    const bool isq = (cb < 16);
    const float* nw = isq ? qnw : knw;
    u16* outp = isq ? qcat : kcat;
    const int hb = isq ? (16 * 2048) : (4 * 2048);
    const int hh = isq ? cb : (cb - 16);
#pragma unroll
    for (int m = 0; m < 4; ++m)
#pragma unroll
      for (int r = 0; r < 4; ++r) {
        int rl = wr * 64 + m * 16 + lg * 4 + r;
        float ss = red[rl][0] + red[rl][1];
        float rn = rsqrtf(ss * (1.f / 128.f) + 1e-6f) * (isq ? QS : 1.f);
        int token = row0 + rl;
        int bb = token >> 11, s = token & 2047;
        size_t ob = ((size_t)(bb * hb) + (size_t)hh * 2048 + s) * 160;
#pragma unroll
        for (int n = 0; n < 4; ++n) {
          int d = wc * 64 + n * 16 + lr;
          outp[ob + d] = f2bf(acc[m][n][r] * rn * nw[d]);
        }
      }
    // behavior-embed norm + concat: one token per thread (tokens 0..127), vectorized
    if (tid < 128) {
      int token = row0 + tid;
      int bb = token >> 11, s = token & 2047;
      int idx = bidx[token];
      const float* ep;
      const float* bw;
      float qs;
      size_t ob;
      if (isq) {
        ep = qbe_t + idx * 512 + hh * 32;
        bw = qbn;
        qs = QS;
        ob = ((size_t)(bb * 16 + hh) * 2048 + s) * 160 + 128;
      } else {
        ep = kbe_t + idx * 128 + hh * 32;
        bw = kbn;
        qs = 1.f;
        ob = ((size_t)(bb * 4 + hh) * 2048 + s) * 160 + 128;
      }
      float4 e4[8];
#pragma unroll
      for (int q = 0; q < 8; ++q) e4[q] = reinterpret_cast<const float4*>(ep)[q];
      const float* ef = reinterpret_cast<const float*>(e4);
      float ss = 0.f;
#pragma unroll
      for (int e = 0; e < 32; ++e) ss += ef[e] * ef[e];
      float rn = rsqrtf(ss * (1.f / 32.f) + 1e-6f) * qs;
#pragma unroll
      for (int e = 0; e < 16; ++e) {
        u32 pk2 = (u32)f2bf(ef[2 * e] * rn * bw[2 * e]) |
                  ((u32)f2bf(ef[2 * e + 1] * rn * bw[2 * e + 1]) << 16);
        *reinterpret_cast<u32*>(&outp[ob + 2 * e]) = pk2;  // (ob+128)*2 is 4B-aligned
      }
    }
  } else {
    // v-head: transpose write vt[(bb*4+kv)*128 + d][s]
    const int kv = cb - 20;
#pragma unroll
    for (int m = 0; m < 4; ++m)
#pragma unroll
      for (int r = 0; r < 4; ++r) {
        int token = row0 + wr * 64 + m * 16 + lg * 4 + r;
        int bb = token >> 11, s = token & 2047;
#pragma unroll
        for (int n = 0; n < 4; ++n) {
          int d = wc * 64 + n * 16 + lr;
          vt[((size_t)(bb * 4 + kv) * 128 + d) * 2048 + s] = f2bf(acc[m][n][r]);
        }
      }
  }
}

// ---------------- flash attention v8 + balanced g-mapping (round-16 frontier) ----------------
__global__ __launch_bounds__(256, 2) void attn(const u16* __restrict__ qcat,
                                               const u16* __restrict__ kcat,
                                               const u16* __restrict__ vt,
                                               u16* __restrict__ aout) {
  __shared__ __align__(16) u16 Kls[2][10240];  // [64 rows][20 granules of 8] swizzled
  __shared__ __align__(16) u16 Vls[8192];      // V^T [128 d][8 granules of 8 keys] swizzled
  const int tid = threadIdx.x;
  const int blk = blockIdx.x;
  const int kvh = blk & 3;
  const int b = (blk >> 2) & 1;
  const int hq = (blk >> 3) & 3;
  const int gsel = blk >> 5;  // 0..15
  const int g = (gsel < 8) ? gsel : 23 - gsel;  // 0..7 then 15..8 (pairs sum to 15)
  const int h = kvh * 4 + hq;
  const int w = tid >> 6;
  const int lane = tid & 63;
  const int lg = lane >> 4, lr = lane & 15;
  const int qb_a = g * 4 + w;        // 0..63
  const int qb_b = 127 - qb_a;       // 64..127
  const int qpa = qb_a * 16 + lr;
  const int qpb = qb_b * 16 + lr;
  const int nt = 32 - g;             // tiles: uniform across the block's waves

  const u16* qpA = qcat + ((size_t)(b * 16 + h) * 2048 + qb_a * 16) * 160;
  const u16* qpB = qcat + ((size_t)(b * 16 + h) * 2048 + qb_b * 16) * 160;
  bf16x8 qfa[5], qfb[5];
#pragma unroll
  for (int c = 0; c < 5; ++c) {
    qfa[c] = ldfrag(qpA + lr * 160 + c * 32 + lg * 8);
    qfb[c] = ldfrag(qpB + lr * 160 + c * 32 + lg * 8);
  }

  const u16* kbp = kcat + (size_t)(b * 4 + kvh) * 2048 * 160;
  const u16* vbp = vt + (size_t)(b * 4 + kvh) * 128 * 2048;

  auto stageK = [&](int buf, int kt) {
    const u16* ksrc = kbp + (size_t)kt * (64 * 160);
#pragma unroll
    for (int it = 0; it < 5; ++it) {
      int G = it * 256 + tid;
      int r = G / 20, p = G - r * 20;
      int gs = p ^ ((r >> 1) & 3);
      gld16(ksrc + r * 160 + gs * 8, &Kls[buf][G * 8]);
    }
  };
  auto stageV = [&](int kt) {
    const u16* vsrc = vbp + kt * 64;
#pragma unroll
    for (int it = 0; it < 4; ++it) {
      int G = it * 256 + tid;
      int r = G >> 3, p = G & 7;
      int gs = p ^ (r & 7);
      gld16(vsrc + (size_t)r * 2048 + gs * 8, &Vls[G * 8]);
    }
  };

  float ma = -INFINITY, la = 0.f, mb = -INFINITY, lb = 0.f;
  f32x4 acc_a[8] = {}, acc_b[8] = {};

  stageK(0, 0);
  stageV(0);
  __syncthreads();

  for (int kt = 0; kt < nt; ++kt) {
    const int buf = kt & 1;
    const bool aact = (kt <= g);
    if (kt + 1 < nt) stageK(buf ^ 1, kt + 1);

    f32x4 sa[4] = {}, sb[4] = {};
#pragma unroll
    for (int c = 0; c < 5; ++c) {
      bf16x8 kf[4];
#pragma unroll
      for (int i = 0; i < 4; ++i) {
        int r = i * 16 + lr;
        int p = (c * 4 + lg) ^ ((r >> 1) & 3);
        kf[i] = ldfrag(&Kls[buf][(r * 20 + p) * 8]);
      }
#pragma unroll
      for (int i = 0; i < 4; ++i)
        sb[i] = __builtin_amdgcn_mfma_f32_16x16x32_bf16(kf[i], qfb[c], sb[i], 0, 0, 0);
      if (aact)
#pragma unroll
        for (int i = 0; i < 4; ++i)
          sa[i] = __builtin_amdgcn_mfma_f32_16x16x32_bf16(kf[i], qfa[c], sa[i], 0, 0, 0);
    }

    // --- softmax in exp2 domain (q pre-scaled by SCALE*log2e), defer-max THR=8 ---
    s16x4 pka[4], pkb[4];
    auto soft = [&](f32x4 (&st)[4], float& mm, float& ls, f32x4 (&ac)[8], s16x4 (&pk)[4],
                    bool masked, int qpos) {
      float vmax = -INFINITY;
#pragma unroll
      for (int i = 0; i < 4; ++i)
#pragma unroll
        for (int r = 0; r < 4; ++r) {
          float v = st[i][r];
          if (masked && (kt * 64 + i * 16 + 4 * lg + r > qpos)) v = -INFINITY;
          st[i][r] = v;
          vmax = fmaxf(vmax, v);
        }
      vmax = fmaxf(vmax, __shfl_xor(vmax, 16));
      vmax = fmaxf(vmax, __shfl_xor(vmax, 32));
      bool skip = __all(vmax <= mm + 8.f);  // defer-max: P bounded by 2^8
      float mn = skip ? mm : fmaxf(mm, vmax);
      float rs = 0.f;
#pragma unroll
      for (int i = 0; i < 4; ++i)
#pragma unroll
        for (int r = 0; r < 4; ++r) {
          float p = exp2f(st[i][r] - mn);
          st[i][r] = p;
          rs += p;
        }
      rs += __shfl_xor(rs, 16);
      rs += __shfl_xor(rs, 32);
      if (skip) {
        ls += rs;
      } else {
        float corr = exp2f(mm - mn);
        ls = ls * corr + rs;
        mm = mn;
        float c4[4];
#pragma unroll
        for (int r = 0; r < 4; ++r) c4[r] = __shfl(corr, 4 * lg + r);
#pragma unroll
        for (int dt = 0; dt < 8; ++dt)
#pragma unroll
          for (int r = 0; r < 4; ++r) ac[dt][r] *= c4[r];
      }
#pragma unroll
      for (int i = 0; i < 4; ++i) {
        pk[i][0] = (short)f2bf_fast(st[i][0]);
        pk[i][1] = (short)f2bf_fast(st[i][1]);
        pk[i][2] = (short)f2bf_fast(st[i][2]);
        pk[i][3] = (short)f2bf_fast(st[i][3]);
      }
    };
    soft(sb, mb, lb, acc_b, pkb, kt == nt - 1, qpb);
    if (aact) soft(sa, ma, la, acc_a, pka, kt == g, qpa);

    __syncthreads();  // #1: V(kt) staged by all waves is complete

#pragma unroll
    for (int ks = 0; ks < 4; ++ks) {
      s16x4 vf[8];
#pragma unroll
      for (int dt = 0; dt < 8; ++dt) {
        int r = dt * 16 + lr;
        int p = (ks * 2 + (lg >> 1)) ^ (r & 7);
        vf[dt] = *reinterpret_cast<const s16x4*>(&Vls[(r * 8 + p) * 8 + (lg & 1) * 4]);
      }
#pragma unroll
      for (int dt = 0; dt < 8; ++dt) acc_b[dt] = mfma16x16(pkb[ks], vf[dt], acc_b[dt]);
      if (aact)
#pragma unroll
        for (int dt = 0; dt < 8; ++dt) acc_a[dt] = mfma16x16(pka[ks], vf[dt], acc_a[dt]);
    }

    __syncthreads();  // #2: all waves done reading Vls
    if (kt + 1 < nt) stageV(kt + 1);
  }

  float inva[4], invb[4];
#pragma unroll
  for (int r = 0; r < 4; ++r) {
    inva[r] = 1.f / __shfl(la, 4 * lg + r);
    invb[r] = 1.f / __shfl(lb, 4 * lg + r);
  }
#pragma unroll
  for (int dt = 0; dt < 8; ++dt)
#pragma unroll
    for (int r = 0; r < 4; ++r) {
      int rowa = qb_a * 16 + 4 * lg + r;
      int rowb = qb_b * 16 + 4 * lg + r;
      aout[((size_t)(b * 2048 + rowa) * 16 + h) * 128 + dt * 16 + lr] =
          f2bf(acc_a[dt][r] * inva[r]);
      aout[((size_t)(b * 2048 + rowb) * 16 + h) * 128 + dt * 16 + lr] =
          f2bf(acc_b[dt][r] * invb[r]);
    }
}

extern "C" void kernel_launch(void* const* d_in, const int* in_sizes, int n_in,
                              void* d_out, int out_size, void* d_ws, size_t ws_size,
                              hipStream_t stream) {
  const float* hs = (const float*)d_in[0];
  const int* bidx = (const int*)d_in[1];
  const float* qw = (const float*)d_in[2];
  const float* kw = (const float*)d_in[3];
  const float* vw = (const float*)d_in[4];
  const float* ow = (const float*)d_in[5];
  const float* qnw = (const float*)d_in[6];
  const float* knw = (const float*)d_in[7];
  const float* qbe_t = (const float*)d_in[8];
  const float* kbe_t = (const float*)d_in[9];
  const float* qbn = (const float*)d_in[10];
  const float* kbn = (const float*)d_in[11];

  u16* ws = (u16*)d_ws;
  u16* hs_bf = ws;                       // 4096*2048
  u16* wqkv = hs_bf + 8388608;           // 3072*2048
  u16* ow_bf = wqkv + 6291456;           // 2048*2048
  u16* qkv = ow_bf + 4194304;            // (unused after fusion; kept for layout stability)
  u16* qcat = qkv + 12582912;            // 2*16*2048*160
  u16* kcat = qcat + 10485760;           // 2*4*2048*160
  u16* vt = kcat + 2621440;              // 2*4*128*2048
  u16* attn_o = vt + 2097152;            // 4096*2048

  conv_all<<<4608, 256, 0, stream>>>(hs, qw, kw, vw, ow, hs_bf, wqkv, ow_bf);

  gemm_bt<2><<<dim3((4096 / 128) * (3072 / 128)), 256, 0, stream>>>(
      hs_bf, wqkv, nullptr, 4096, 3072, 2048,
      bidx, qnw, knw, qbe_t, kbe_t, qbn, kbn, qcat, kcat, vt);

  attn<<<512, 256, 0, stream>>>(qcat, kcat, vt, attn_o);

  gemm_bt<0><<<dim3((4096 / 128) * (2048 / 128)), 256, 0, stream>>>(
      attn_o, ow_bf, (void*)d_out, 4096, 2048, 2048,
      nullptr, nullptr, nullptr, nullptr, nullptr, nullptr, nullptr,
      nullptr, nullptr, nullptr);
}

// Round 21
// 216.352 us; speedup vs baseline: 1.2476x; 1.0009x over previous
//
#include <hip/hip_runtime.h>

typedef unsigned short u16;
typedef unsigned int u32;
typedef __bf16 bf16x8 __attribute__((ext_vector_type(8)));
typedef __bf16 b16x4 __attribute__((ext_vector_type(4)));
typedef short s16x4 __attribute__((ext_vector_type(4)));
typedef float f32x4 __attribute__((ext_vector_type(4)));

#define SCALE 0.07905694150420949f   // (128+32)^-0.5
#define LOG2E 1.4426950408889634f

__device__ __forceinline__ float bf2f(u16 h) { return __uint_as_float(((u32)h) << 16); }
__device__ __forceinline__ u16 f2bf(float f) {  // RNE-ish
  u32 u = __float_as_uint(f);
  u += 0x7fffu + ((u >> 16) & 1u);
  return (u16)(u >> 16);
}
__device__ __forceinline__ u16 f2bf_fast(float f) {  // round-half-up, for attention P
  return (u16)((__float_as_uint(f) + 0x8000u) >> 16);
}
__device__ __forceinline__ bf16x8 ldfrag(const u16* p) {
  int4 t = *reinterpret_cast<const int4*>(p);
  return __builtin_bit_cast(bf16x8, t);
}

// 16x16x16 bf16 MFMA (A,B = 4 bf16 per lane, k = 4*(lane>>4)+j)
__device__ __forceinline__ f32x4 mfma16x16(s16x4 a, s16x4 b, f32x4 c) {
#if __has_builtin(__builtin_amdgcn_mfma_f32_16x16x16bf16_1k)
  return __builtin_amdgcn_mfma_f32_16x16x16bf16_1k(a, b, c, 0, 0, 0);
#elif __has_builtin(__builtin_amdgcn_mfma_f32_16x16x16_bf16)
  return __builtin_amdgcn_mfma_f32_16x16x16_bf16(__builtin_bit_cast(b16x4, a),
                                                 __builtin_bit_cast(b16x4, b), c, 0, 0, 0);
#else
  asm volatile("s_nop 2\n\tv_mfma_f32_16x16x16_bf16 %0, %1, %2, %0"
               : "+v"(c) : "v"(a), "v"(b));
  return c;
#endif
}

// async global->LDS, 16B per lane (dest = wave-uniform base + lane*16)
__device__ __forceinline__ void gld16(const u16* g, u16* l) {
  __builtin_amdgcn_global_load_lds((const __attribute__((address_space(1))) u32*)(const void*)g,
                                   (__attribute__((address_space(3))) u32*)(void*)l, 16, 0, 0);
}

// ---------------- merged f32 -> bf16 converts (one launch) ----------------
__global__ void conv_all(const float* __restrict__ hs, const float* __restrict__ qw,
                         const float* __restrict__ kw, const float* __restrict__ vw,
                         const float* __restrict__ ow, u16* __restrict__ hs_bf,
                         u16* __restrict__ wqkv, u16* __restrict__ ow_bf) {
  const int total = 4718592;
  for (int i = blockIdx.x * blockDim.x + threadIdx.x; i < total; i += gridDim.x * blockDim.x) {
    const float* src;
    u16* dst;
    int j = i;
    if (j < 2097152) {
      src = hs; dst = hs_bf;
    } else if (j < 3145728) {
      j -= 2097152; src = qw; dst = wqkv;
    } else if (j < 3407872) {
      j -= 3145728; src = kw; dst = wqkv + 4194304;
    } else if (j < 3670016) {
      j -= 3407872; src = vw; dst = wqkv + 5242880;
    } else {
      j -= 3670016; src = ow; dst = ow_bf;
    }
    float4 v = reinterpret_cast<const float4*>(src)[j];
    ushort4 o = {f2bf(v.x), f2bf(v.y), f2bf(v.z), f2bf(v.w)};
    reinterpret_cast<ushort4*>(dst)[j] = o;
  }
}

// ---------------- GEMM: 128x128, counted vmcnt(8), 2-deep (round-10 proven loop) ----------------
// MODE 0: plain f32 C-write (O-proj).
// MODE 2: fused QKV epilogue — per-head RMSNorm, behavior-embed norm+concat, V transpose.
template <int MODE>
__global__ __launch_bounds__(256, 2) void gemm_bt(
    const u16* __restrict__ A, const u16* __restrict__ Bw, void* __restrict__ Cv,
    int M, int N, int K,
    const int* __restrict__ bidx, const float* __restrict__ qnw, const float* __restrict__ knw,
    const float* __restrict__ qbe_t, const float* __restrict__ kbe_t,
    const float* __restrict__ qbn, const float* __restrict__ kbn,
    u16* __restrict__ qcat, u16* __restrict__ kcat, u16* __restrict__ vt) {
  __shared__ __align__(16) u16 As[2][8192];
  __shared__ __align__(16) u16 Bs[2][8192];
  __shared__ float red[(MODE == 2) ? 128 : 1][2];
  const int tid = threadIdx.x;
  const int nbn = N >> 7;
  const int cpx = gridDim.x >> 3;
  const int swz = (blockIdx.x & 7) * cpx + (blockIdx.x >> 3);
  const int bm = swz / nbn, bn = swz % nbn;
  const int row0 = bm << 7, col0 = bn << 7;
  const int lane = tid & 63, w = tid >> 6;
  const int lg = lane >> 4, lr = lane & 15;
  const int wr = w >> 1, wc = w & 1;
  const int nt = K >> 6;

  auto stage = [&](int slot, int t) {
    const size_t k0 = (size_t)t << 6;
#pragma unroll
    for (int it = 0; it < 4; ++it) {
      int G = it * 256 + tid;
      int r = G >> 3, p = G & 7;
      int gs = p ^ (r & 7);
      gld16(&A[(size_t)(row0 + r) * K + k0 + gs * 8], &As[slot][(size_t)G * 8]);
      gld16(&Bw[(size_t)(col0 + r) * K + k0 + gs * 8], &Bs[slot][(size_t)G * 8]);
    }
  };

  f32x4 acc[4][4] = {};
  stage(0, 0);
  if (nt > 1) stage(1, 1);

  for (int t = 0; t < nt; ++t) {
    const int slot = t & 1;
    if (t + 1 < nt) {
      asm volatile("s_waitcnt vmcnt(8)" ::: "memory");
    } else {
      asm volatile("s_waitcnt vmcnt(0)" ::: "memory");
    }
    __builtin_amdgcn_s_barrier();
    __builtin_amdgcn_sched_barrier(0);
#pragma unroll
    for (int kk = 0; kk < 2; ++kk) {
      bf16x8 af[4], bv[4];
#pragma unroll
      for (int m = 0; m < 4; ++m) {
        int r = wr * 64 + m * 16 + lr;
        int g = (kk * 4 + lg) ^ (lr & 7);
        af[m] = ldfrag(&As[slot][r * 64 + g * 8]);
      }
#pragma unroll
      for (int n = 0; n < 4; ++n) {
        int r = wc * 64 + n * 16 + lr;
        int g = (kk * 4 + lg) ^ (lr & 7);
        bv[n] = ldfrag(&Bs[slot][r * 64 + g * 8]);
      }
#pragma unroll
      for (int m = 0; m < 4; ++m)
#pragma unroll
        for (int n = 0; n < 4; ++n)
          acc[m][n] = __builtin_amdgcn_mfma_f32_16x16x32_bf16(af[m], bv[n], acc[m][n], 0, 0, 0);
    }
    __builtin_amdgcn_sched_barrier(0);
    __builtin_amdgcn_s_barrier();
    if (t + 2 < nt) stage(slot, t + 2);
  }

  if (MODE == 0) {
#pragma unroll
    for (int m = 0; m < 4; ++m)
#pragma unroll
      for (int n = 0; n < 4; ++n)
#pragma unroll
        for (int r = 0; r < 4; ++r) {
          int row = row0 + wr * 64 + m * 16 + lg * 4 + r;
          int col = col0 + wc * 64 + n * 16 + lr;
          ((float*)Cv)[(size_t)row * N + col] = acc[m][n][r];
        }
    return;
  }

  // ---------------- fused QKV epilogue (MODE 2) ----------------
  const int cb = col0 >> 7;  // 0..15 q-head, 16..19 k-head, 20..23 v-head
  const float QS = SCALE * LOG2E;

  if (cb < 20) {
    float part[4][4];
#pragma unroll
    for (int m = 0; m < 4; ++m)
#pragma unroll
      for (int r = 0; r < 4; ++r) {
        float s = 0.f;
#pragma unroll
        for (int n = 0; n < 4; ++n) s += acc[m][n][r] * acc[m][n][r];
#pragma unroll
        for (int o = 1; o < 16; o <<= 1) s += __shfl_xor(s, o);  // reduce over lr
        part[m][r] = s;
      }
    if (lr == 0) {
#pragma unroll
      for (int m = 0; m < 4; ++m)
#pragma unroll
        for (int r = 0; r < 4; ++r) red[wr * 64 + m * 16 + lg * 4 + r][wc] = part[m][r];
    }
    __syncthreads();

    const bool isq = (cb < 16);
    const float* nw = isq ? qnw : knw;
    u16* outp = isq ? qcat : kcat;
    const int hb = isq ? (16 * 2048) : (4 * 2048);
    const int hh = isq ? cb : (cb - 16);
#pragma unroll
    for (int m = 0; m < 4; ++m)
#pragma unroll
      for (int r = 0; r < 4; ++r) {
        int rl = wr * 64 + m * 16 + lg * 4 + r;
        float ss = red[rl][0] + red[rl][1];
        float rn = rsqrtf(ss * (1.f / 128.f) + 1e-6f) * (isq ? QS : 1.f);
        int token = row0 + rl;
        int bb = token >> 11, s = token & 2047;
        size_t ob = ((size_t)(bb * hb) + (size_t)hh * 2048 + s) * 160;
#pragma unroll
        for (int n = 0; n < 4; ++n) {
          int d = wc * 64 + n * 16 + lr;
          outp[ob + d] = f2bf(acc[m][n][r] * rn * nw[d]);
        }
      }
    // behavior-embed norm + concat: one token per thread (tokens 0..127), vectorized
    if (tid < 128) {
      int token = row0 + tid;
      int bb = token >> 11, s = token & 2047;
      int idx = bidx[token];
      const float* ep;
      const float* bw;
      float qs;
      size_t ob;
      if (isq) {
        ep = qbe_t + idx * 512 + hh * 32;
        bw = qbn;
        qs = QS;
        ob = ((size_t)(bb * 16 + hh) * 2048 + s) * 160 + 128;
      } else {
        ep = kbe_t + idx * 128 + hh * 32;
        bw = kbn;
        qs = 1.f;
        ob = ((size_t)(bb * 4 + hh) * 2048 + s) * 160 + 128;
      }
      float4 e4[8];
#pragma unroll
      for (int q = 0; q < 8; ++q) e4[q] = reinterpret_cast<const float4*>(ep)[q];
      const float* ef = reinterpret_cast<const float*>(e4);
      float ss = 0.f;
#pragma unroll
      for (int e = 0; e < 32; ++e) ss += ef[e] * ef[e];
      float rn = rsqrtf(ss * (1.f / 32.f) + 1e-6f) * qs;
#pragma unroll
      for (int e = 0; e < 16; ++e) {
        u32 pk2 = (u32)f2bf(ef[2 * e] * rn * bw[2 * e]) |
                  ((u32)f2bf(ef[2 * e + 1] * rn * bw[2 * e + 1]) << 16);
        *reinterpret_cast<u32*>(&outp[ob + 2 * e]) = pk2;  // (ob+128)*2 is 4B-aligned
      }
    }
  } else {
    // v-head: transpose write vt[(bb*4+kv)*128 + d][s]
    const int kv = cb - 20;
#pragma unroll
    for (int m = 0; m < 4; ++m)
#pragma unroll
      for (int r = 0; r < 4; ++r) {
        int token = row0 + wr * 64 + m * 16 + lg * 4 + r;
        int bb = token >> 11, s = token & 2047;
#pragma unroll
        for (int n = 0; n < 4; ++n) {
          int d = wc * 64 + n * 16 + lr;
          vt[((size_t)(bb * 4 + kv) * 128 + d) * 2048 + s] = f2bf(acc[m][n][r]);
        }
      }
  }
}

// ---------------- flash attention v8 + balanced g-mapping (round-16 frontier) ----------------
__global__ __launch_bounds__(256, 2) void attn(const u16* __restrict__ qcat,
                                               const u16* __restrict__ kcat,
                                               const u16* __restrict__ vt,
                                               u16* __restrict__ aout) {
  __shared__ __align__(16) u16 Kls[2][10240];  // [64 rows][20 granules of 8] swizzled
  __shared__ __align__(16) u16 Vls[8192];      // V^T [128 d][8 granules of 8 keys] swizzled
  const int tid = threadIdx.x;
  const int blk = blockIdx.x;
  const int kvh = blk & 3;
  const int b = (blk >> 2) & 1;
  const int hq = (blk >> 3) & 3;
  const int gsel = blk >> 5;  // 0..15
  const int g = (gsel < 8) ? gsel : 23 - gsel;  // 0..7 then 15..8 (pairs sum to 15)
  const int h = kvh * 4 + hq;
  const int w = tid >> 6;
  const int lane = tid & 63;
  const int lg = lane >> 4, lr = lane & 15;
  const int qb_a = g * 4 + w;        // 0..63
  const int qb_b = 127 - qb_a;       // 64..127
  const int qpa = qb_a * 16 + lr;
  const int qpb = qb_b * 16 + lr;
  const int nt = 32 - g;             // tiles: uniform across the block's waves

  const u16* qpA = qcat + ((size_t)(b * 16 + h) * 2048 + qb_a * 16) * 160;
  const u16* qpB = qcat + ((size_t)(b * 16 + h) * 2048 + qb_b * 16) * 160;
  bf16x8 qfa[5], qfb[5];
#pragma unroll
  for (int c = 0; c < 5; ++c) {
    qfa[c] = ldfrag(qpA + lr * 160 + c * 32 + lg * 8);
    qfb[c] = ldfrag(qpB + lr * 160 + c * 32 + lg * 8);
  }

  const u16* kbp = kcat + (size_t)(b * 4 + kvh) * 2048 * 160;
  const u16* vbp = vt + (size_t)(b * 4 + kvh) * 128 * 2048;

  auto stageK = [&](int buf, int kt) {
    const u16* ksrc = kbp + (size_t)kt * (64 * 160);
#pragma unroll
    for (int it = 0; it < 5; ++it) {
      int G = it * 256 + tid;
      int r = G / 20, p = G - r * 20;
      int gs = p ^ ((r >> 1) & 3);
      gld16(ksrc + r * 160 + gs * 8, &Kls[buf][G * 8]);
    }
  };
  auto stageV = [&](int kt) {
    const u16* vsrc = vbp + kt * 64;
#pragma unroll
    for (int it = 0; it < 4; ++it) {
      int G = it * 256 + tid;
      int r = G >> 3, p = G & 7;
      int gs = p ^ (r & 7);
      gld16(vsrc + (size_t)r * 2048 + gs * 8, &Vls[G * 8]);
    }
  };

  float ma = -INFINITY, la = 0.f, mb = -INFINITY, lb = 0.f;
  f32x4 acc_a[8] = {}, acc_b[8] = {};

  stageK(0, 0);
  stageV(0);
  __syncthreads();

  for (int kt = 0; kt < nt; ++kt) {
    const int buf = kt & 1;
    const bool aact = (kt <= g);
    if (kt + 1 < nt) stageK(buf ^ 1, kt + 1);

    f32x4 sa[4] = {}, sb[4] = {};
#pragma unroll
    for (int c = 0; c < 5; ++c) {
      bf16x8 kf[4];
#pragma unroll
      for (int i = 0; i < 4; ++i) {
        int r = i * 16 + lr;
        int p = (c * 4 + lg) ^ ((r >> 1) & 3);
        kf[i] = ldfrag(&Kls[buf][(r * 20 + p) * 8]);
      }
#pragma unroll
      for (int i = 0; i < 4; ++i)
        sb[i] = __builtin_amdgcn_mfma_f32_16x16x32_bf16(kf[i], qfb[c], sb[i], 0, 0, 0);
      if (aact)
#pragma unroll
        for (int i = 0; i < 4; ++i)
          sa[i] = __builtin_amdgcn_mfma_f32_16x16x32_bf16(kf[i], qfa[c], sa[i], 0, 0, 0);
    }

    // --- softmax in exp2 domain (q pre-scaled by SCALE*log2e), defer-max THR=8 ---
    s16x4 pka[4], pkb[4];
    auto soft = [&](f32x4 (&st)[4], float& mm, float& ls, f32x4 (&ac)[8], s16x4 (&pk)[4],
                    bool masked, int qpos) {
      float vmax = -INFINITY;
#pragma unroll
      for (int i = 0; i < 4; ++i)
#pragma unroll
        for (int r = 0; r < 4; ++r) {
          float v = st[i][r];
          if (masked && (kt * 64 + i * 16 + 4 * lg + r > qpos)) v = -INFINITY;
          st[i][r] = v;
          vmax = fmaxf(vmax, v);
        }
      vmax = fmaxf(vmax, __shfl_xor(vmax, 16));
      vmax = fmaxf(vmax, __shfl_xor(vmax, 32));
      bool skip = __all(vmax <= mm + 8.f);  // defer-max: P bounded by 2^8
      float mn = skip ? mm : fmaxf(mm, vmax);
      float rs = 0.f;
#pragma unroll
      for (int i = 0; i < 4; ++i)
#pragma unroll
        for (int r = 0; r < 4; ++r) {
          float p = exp2f(st[i][r] - mn);
          st[i][r] = p;
          rs += p;
        }
      rs += __shfl_xor(rs, 16);
      rs += __shfl_xor(rs, 32);
      if (skip) {
        ls += rs;
      } else {
        float corr = exp2f(mm - mn);
        ls = ls * corr + rs;
        mm = mn;
        float c4[4];
#pragma unroll
        for (int r = 0; r < 4; ++r) c4[r] = __shfl(corr, 4 * lg + r);
#pragma unroll
        for (int dt = 0; dt < 8; ++dt)
#pragma unroll
          for (int r = 0; r < 4; ++r) ac[dt][r] *= c4[r];
      }
#pragma unroll
      for (int i = 0; i < 4; ++i) {
        pk[i][0] = (short)f2bf_fast(st[i][0]);
        pk[i][1] = (short)f2bf_fast(st[i][1]);
        pk[i][2] = (short)f2bf_fast(st[i][2]);
        pk[i][3] = (short)f2bf_fast(st[i][3]);
      }
    };
    soft(sb, mb, lb, acc_b, pkb, kt == nt - 1, qpb);
    if (aact) soft(sa, ma, la, acc_a, pka, kt == g, qpa);

    __syncthreads();  // #1: V(kt) staged by all waves is complete

#pragma unroll
    for (int ks = 0; ks < 4; ++ks) {
      s16x4 vf[8];
#pragma unroll
      for (int dt = 0; dt < 8; ++dt) {
        int r = dt * 16 + lr;
        int p = (ks * 2 + (lg >> 1)) ^ (r & 7);
        vf[dt] = *reinterpret_cast<const s16x4*>(&Vls[(r * 8 + p) * 8 + (lg & 1) * 4]);
      }
#pragma unroll
      for (int dt = 0; dt < 8; ++dt) acc_b[dt] = mfma16x16(pkb[ks], vf[dt], acc_b[dt]);
      if (aact)
#pragma unroll
        for (int dt = 0; dt < 8; ++dt) acc_a[dt] = mfma16x16(pka[ks], vf[dt], acc_a[dt]);
    }

    __syncthreads();  // #2: all waves done reading Vls
    if (kt + 1 < nt) stageV(kt + 1);
  }

  float inva[4], invb[4];
#pragma unroll
  for (int r = 0; r < 4; ++r) {
    inva[r] = 1.f / __shfl(la, 4 * lg + r);
    invb[r] = 1.f / __shfl(lb, 4 * lg + r);
  }
#pragma unroll
  for (int dt = 0; dt < 8; ++dt)
#pragma unroll
    for (int r = 0; r < 4; ++r) {
      int rowa = qb_a * 16 + 4 * lg + r;
      int rowb = qb_b * 16 + 4 * lg + r;
      aout[((size_t)(b * 2048 + rowa) * 16 + h) * 128 + dt * 16 + lr] =
          f2bf(acc_a[dt][r] * inva[r]);
      aout[((size_t)(b * 2048 + rowb) * 16 + h) * 128 + dt * 16 + lr] =
          f2bf(acc_b[dt][r] * invb[r]);
    }
}

extern "C" void kernel_launch(void* const* d_in, const int* in_sizes, int n_in,
                              void* d_out, int out_size, void* d_ws, size_t ws_size,
                              hipStream_t stream) {
  const float* hs = (const float*)d_in[0];
  const int* bidx = (const int*)d_in[1];
  const float* qw = (const float*)d_in[2];
  const float* kw = (const float*)d_in[3];
  const float* vw = (const float*)d_in[4];
  const float* ow = (const float*)d_in[5];
  const float* qnw = (const float*)d_in[6];
  const float* knw = (const float*)d_in[7];
  const float* qbe_t = (const float*)d_in[8];
  const float* kbe_t = (const float*)d_in[9];
  const float* qbn = (const float*)d_in[10];
  const float* kbn = (const float*)d_in[11];

  u16* ws = (u16*)d_ws;
  u16* hs_bf = ws;                       // 4096*2048
  u16* wqkv = hs_bf + 8388608;           // 3072*2048
  u16* ow_bf = wqkv + 6291456;           // 2048*2048
  u16* qkv = ow_bf + 4194304;            // (unused after fusion; kept for layout stability)
  u16* qcat = qkv + 12582912;            // 2*16*2048*160
  u16* kcat = qcat + 10485760;           // 2*4*2048*160
  u16* vt = kcat + 2621440;              // 2*4*128*2048
  u16* attn_o = vt + 2097152;            // 4096*2048

  conv_all<<<4608, 256, 0, stream>>>(hs, qw, kw, vw, ow, hs_bf, wqkv, ow_bf);

  gemm_bt<2><<<dim3((4096 / 128) * (3072 / 128)), 256, 0, stream>>>(
      hs_bf, wqkv, nullptr, 4096, 3072, 2048,
      bidx, qnw, knw, qbe_t, kbe_t, qbn, kbn, qcat, kcat, vt);

  attn<<<512, 256, 0, stream>>>(qcat, kcat, vt, attn_o);

  gemm_bt<0><<<dim3((4096 / 128) * (2048 / 128)), 256, 0, stream>>>(
      attn_o, ow_bf, (void*)d_out, 4096, 2048, 2048,
      nullptr, nullptr, nullptr, nullptr, nullptr, nullptr, nullptr,
      nullptr, nullptr, nullptr);
}